// Round 3
// baseline (1100.244 us; speedup 1.0000x reference)
//
#include <hip/hip_runtime.h>

#define CDIV(a,b) (((a)+(b)-1)/(b))

// ---------------- degree / dinv ----------------
__global__ __launch_bounds__(256) void hg_deg_count(const int* __restrict__ dst, int* __restrict__ deg, int E){
    int e0 = (blockIdx.x*256 + threadIdx.x)*4;
    if (e0 + 3 < E){
        const int4 d = *(const int4*)(dst + e0);
        atomicAdd(&deg[d.x], 1); atomicAdd(&deg[d.y], 1);
        atomicAdd(&deg[d.z], 1); atomicAdd(&deg[d.w], 1);
    } else {
        for (int e = e0; e < E; ++e) atomicAdd(&deg[dst[e]], 1);
    }
}

__global__ __launch_bounds__(256) void hg_dinv(const int* __restrict__ deg, float* __restrict__ dinv, int N){
    int v = blockIdx.x*256 + threadIdx.x;
    if (v < N) dinv[v] = rsqrtf((float)(deg[v] + 1));   // +1 self-loop; always > 0
}

// ---------------- exclusive scan of deg -> rowptr ----------------
__global__ __launch_bounds__(256) void hg_scan1(const int* __restrict__ deg, int* __restrict__ rowptr,
                                                int* __restrict__ bsum, int N){
    __shared__ int sh[256];
    const int t = threadIdx.x;
    const int base = blockIdx.x*1024 + t*4;
    int v0=0,v1=0,v2=0,v3=0;
    if (base+0 < N) v0 = deg[base+0];
    if (base+1 < N) v1 = deg[base+1];
    if (base+2 < N) v2 = deg[base+2];
    if (base+3 < N) v3 = deg[base+3];
    const int s = v0+v1+v2+v3;
    sh[t] = s;
    __syncthreads();
    for (int off = 1; off < 256; off <<= 1){
        int x = 0;
        if (t >= off) x = sh[t-off];
        __syncthreads();
        if (t >= off) sh[t] += x;
        __syncthreads();
    }
    const int excl = sh[t] - s;
    if (t == 255) bsum[blockIdx.x] = sh[255];
    if (base+0 < N) rowptr[base+0] = excl;
    if (base+1 < N) rowptr[base+1] = excl + v0;
    if (base+2 < N) rowptr[base+2] = excl + v0+v1;
    if (base+3 < N) rowptr[base+3] = excl + v0+v1+v2;
}

__global__ void hg_scan2(int* __restrict__ bsum, int nb){
    if (threadIdx.x == 0 && blockIdx.x == 0){
        int acc = 0;
        for (int i = 0; i < nb; ++i){ int v = bsum[i]; bsum[i] = acc; acc += v; }
    }
}

__global__ __launch_bounds__(256) void hg_scan3(int* __restrict__ rowptr, const int* __restrict__ bsum,
                                                int N, int E){
    int i = blockIdx.x*256 + threadIdx.x;
    if (i < N) rowptr[i] += bsum[i >> 10];
    if (i == 0) rowptr[N] = E;
}

// ---------------- CSR edge placement (counting sort by dst), 4 edges/thread ----------------
__global__ __launch_bounds__(256) void hg_place(const int* __restrict__ src, const int* __restrict__ dst,
                                                int* __restrict__ cursor, int* __restrict__ csr_src, int E){
    int e0 = (blockIdx.x*256 + threadIdx.x)*4;
    if (e0 + 3 < E){
        const int4 d = *(const int4*)(dst + e0);
        const int4 s = *(const int4*)(src + e0);
        const int p0 = atomicAdd(&cursor[d.x], 1);
        const int p1 = atomicAdd(&cursor[d.y], 1);
        const int p2 = atomicAdd(&cursor[d.z], 1);
        const int p3 = atomicAdd(&cursor[d.w], 1);
        csr_src[p0] = s.x; csr_src[p1] = s.y; csr_src[p2] = s.z; csr_src[p3] = s.w;
    } else {
        for (int e = e0; e < E; ++e){
            int p = atomicAdd(&cursor[dst[e]], 1);
            csr_src[p] = src[e];
        }
    }
}

// ---------------- fused GEMM: G[v][j] = (X[v,:] @ W[:,j]) * dinv[v] ----------------
// 64 rows/block; wave w handles rows [blk*64 + w*16, +16); lane = output col.
// x-row loads are wave-uniform (hardware broadcast); W staged in LDS.
template<int K>
__global__ __launch_bounds__(256) void hg_gemm_scaled(const float* __restrict__ X, const float* __restrict__ W,
                                                      const float* __restrict__ dinv, float* __restrict__ G, int N){
    __shared__ float Wl[K*64];
    for (int i = threadIdx.x; i < K*16; i += 256)
        ((float4*)Wl)[i] = ((const float4*)W)[i];
    __syncthreads();
    const int col  = threadIdx.x & 63;
    const int wid  = threadIdx.x >> 6;
    const int row0 = blockIdx.x * 64 + wid * 16;
    if (row0 >= N) return;

    if (row0 + 15 < N) {
        float acc[16];
        #pragma unroll
        for (int r = 0; r < 16; ++r) acc[r] = 0.f;
        const float* xb = X + (size_t)row0 * K;
        #pragma unroll 4
        for (int k = 0; k < K; k += 4) {
            const float w0 = Wl[(k+0)*64 + col];
            const float w1 = Wl[(k+1)*64 + col];
            const float w2 = Wl[(k+2)*64 + col];
            const float w3 = Wl[(k+3)*64 + col];
            #pragma unroll
            for (int r = 0; r < 16; ++r) {
                const float4 x = *(const float4*)(xb + (size_t)r*K + k);  // wave-uniform -> broadcast
                acc[r] = fmaf(x.w,w3, fmaf(x.z,w2, fmaf(x.y,w1, fmaf(x.x,w0, acc[r]))));
            }
        }
        #pragma unroll
        for (int r = 0; r < 16; ++r)
            G[(size_t)(row0+r)*64 + col] = acc[r] * dinv[row0+r];
    } else {
        for (int r = 0; r < 16; ++r) {
            const int row = row0 + r;
            if (row >= N) break;
            float acc = 0.f;
            const float* xr = X + (size_t)row * K;
            for (int k = 0; k < K; ++k) acc = fmaf(xr[k], Wl[k*64 + col], acc);
            G[(size_t)row*64 + col] = acc * dinv[row];
        }
    }
}

// ---------------- gather-aggregate + fused epilogue ----------------
// one wave per dst node; lane = feature col; out = relu((sum_in g[s] + g[v]) * dinv[v] + b)
__global__ __launch_bounds__(256) void hg_aggregate(const float* __restrict__ g, const int* __restrict__ csr_src,
                                                    const int* __restrict__ rowptr, const float* __restrict__ dinv,
                                                    const float* __restrict__ b, float* __restrict__ outp, int N){
    const int wid  = (blockIdx.x*256 + threadIdx.x) >> 6;
    const int lane = threadIdx.x & 63;
    if (wid >= N) return;
    const int beg = rowptr[wid];
    const int end = rowptr[wid+1];
    float acc = g[(size_t)wid*64 + lane];            // self-loop term
    float a0=0.f,a1=0.f,a2=0.f,a3=0.f,a4=0.f,a5=0.f,a6=0.f,a7=0.f;
    int i = beg;
    for (; i + 8 <= end; i += 8){
        const int s0 = csr_src[i+0]; const int s1 = csr_src[i+1];
        const int s2 = csr_src[i+2]; const int s3 = csr_src[i+3];
        const int s4 = csr_src[i+4]; const int s5 = csr_src[i+5];
        const int s6 = csr_src[i+6]; const int s7 = csr_src[i+7];
        a0 += g[(size_t)s0*64 + lane]; a1 += g[(size_t)s1*64 + lane];
        a2 += g[(size_t)s2*64 + lane]; a3 += g[(size_t)s3*64 + lane];
        a4 += g[(size_t)s4*64 + lane]; a5 += g[(size_t)s5*64 + lane];
        a6 += g[(size_t)s6*64 + lane]; a7 += g[(size_t)s7*64 + lane];
    }
    for (; i < end; ++i)
        a0 += g[(size_t)csr_src[i]*64 + lane];
    acc += ((a0+a1)+(a2+a3)) + ((a4+a5)+(a6+a7));
    outp[(size_t)wid*64 + lane] = fmaxf(fmaf(acc, dinv[wid], b[lane]), 0.f);
}

// ---------------- head: out[v][0:2] = H[v,:] @ Wl + bl ----------------
__global__ __launch_bounds__(256) void hg_head(const float* __restrict__ H, const float* __restrict__ Wl,
                                               const float* __restrict__ bl, float* __restrict__ outp, int N){
    int v = blockIdx.x*256 + threadIdx.x;
    if (v >= N) return;
    const float* h = H + (size_t)v*64;
    float a0 = bl[0], a1 = bl[1];
    #pragma unroll
    for (int k4 = 0; k4 < 16; ++k4) {
        const float4 x = *(const float4*)(h + k4*4);
        const float4 wA = *(const float4*)(Wl + k4*8 + 0);
        const float4 wB = *(const float4*)(Wl + k4*8 + 4);
        a0 = fmaf(x.x, wA.x, a0); a1 = fmaf(x.x, wA.y, a1);
        a0 = fmaf(x.y, wA.z, a0); a1 = fmaf(x.y, wA.w, a1);
        a0 = fmaf(x.z, wB.x, a0); a1 = fmaf(x.z, wB.y, a1);
        a0 = fmaf(x.w, wB.z, a0); a1 = fmaf(x.w, wB.w, a1);
    }
    float2 r; r.x = a0; r.y = a1;
    *(float2*)(outp + (size_t)v*2) = r;
}

// ---------------- orchestration ----------------
static void run_type(const float* x, const int* ei, int E,
                     const float* W1, const float* b1,
                     const float* W2, const float* b2,
                     const float* Wl, const float* bl,
                     float* out, int N,
                     float* bufA, float* bufB, int* deg, float* dinv,
                     int* rowptr, int* cursor, int* bsum, int* csr_src,
                     hipStream_t stream){
    const int* src = ei;
    const int* dst = ei + E;

    // degree + dinv
    hipMemsetAsync(deg, 0, (size_t)N * sizeof(int), stream);
    hg_deg_count<<<CDIV(E,1024), 256, 0, stream>>>(dst, deg, E);
    hg_dinv<<<CDIV(N,256), 256, 0, stream>>>(deg, dinv, N);

    // CSR build (reused by both layers)
    const int nb = CDIV(N, 1024);
    hg_scan1<<<nb, 256, 0, stream>>>(deg, rowptr, bsum, N);
    hg_scan2<<<1, 64, 0, stream>>>(bsum, nb);
    hg_scan3<<<CDIV(N,256), 256, 0, stream>>>(rowptr, bsum, N, E);
    hipMemcpyAsync(cursor, rowptr, (size_t)N * sizeof(int), hipMemcpyDeviceToDevice, stream);
    hg_place<<<CDIV(E,1024), 256, 0, stream>>>(src, dst, cursor, csr_src, E);

    // layer 1
    hg_gemm_scaled<128><<<CDIV(N,64), 256, 0, stream>>>(x, W1, dinv, bufA, N);
    hg_aggregate<<<CDIV(N,4), 256, 0, stream>>>(bufA, csr_src, rowptr, dinv, b1, bufB, N);

    // layer 2
    hg_gemm_scaled<64><<<CDIV(N,64), 256, 0, stream>>>(bufB, W2, dinv, bufA, N);
    hg_aggregate<<<CDIV(N,4), 256, 0, stream>>>(bufA, csr_src, rowptr, dinv, b2, bufB, N);

    // head
    hg_head<<<CDIV(N,256), 256, 0, stream>>>(bufB, Wl, bl, out, N);
}

extern "C" void kernel_launch(void* const* d_in, const int* in_sizes, int n_in,
                              void* d_out, int out_size, void* d_ws, size_t ws_size,
                              hipStream_t stream) {
    const float* x_user = (const float*)d_in[0];
    const float* x_item = (const float*)d_in[1];
    const int*  ei_user = (const int*)d_in[2];
    const int*  ei_item = (const int*)d_in[3];
    const float* W1_user = (const float*)d_in[4];
    const float* b1_user = (const float*)d_in[5];
    const float* W1_item = (const float*)d_in[6];
    const float* b1_item = (const float*)d_in[7];
    const float* W2_user = (const float*)d_in[8];
    const float* b2_user = (const float*)d_in[9];
    const float* W2_item = (const float*)d_in[10];
    const float* b2_item = (const float*)d_in[11];
    const float* Wl_user = (const float*)d_in[12];
    const float* bl_user = (const float*)d_in[13];
    const float* Wl_item = (const float*)d_in[14];
    const float* bl_item = (const float*)d_in[15];

    const int N_user = in_sizes[0] / 128;
    const int N_item = in_sizes[1] / 128;
    const int E_user = in_sizes[2] / 2;
    const int E_item = in_sizes[3] / 2;
    const int NMAX = (N_user > N_item) ? N_user : N_item;
    const int EMAX = (E_user > E_item) ? E_user : E_item;

    char* w = (char*)d_ws;
    float* bufA   = (float*)w;  w += (size_t)NMAX * 64 * sizeof(float);
    float* bufB   = (float*)w;  w += (size_t)NMAX * 64 * sizeof(float);
    int*   deg    = (int*)w;    w += (size_t)NMAX * sizeof(int);
    float* dinv   = (float*)w;  w += (size_t)NMAX * sizeof(float);
    int*   rowptr = (int*)w;    w += ((size_t)NMAX + 1) * sizeof(int);
    int*   cursor = (int*)w;    w += (size_t)NMAX * sizeof(int);
    int*   bsum   = (int*)w;    w += (size_t)CDIV(NMAX,1024) * sizeof(int);
    int*   csr_src= (int*)w;    w += (size_t)EMAX * sizeof(int);

    float* out = (float*)d_out;

    run_type(x_user, ei_user, E_user, W1_user, b1_user, W2_user, b2_user, Wl_user, bl_user,
             out, N_user, bufA, bufB, deg, dinv, rowptr, cursor, bsum, csr_src, stream);
    run_type(x_item, ei_item, E_item, W1_item, b1_item, W2_item, b2_item, Wl_item, bl_item,
             out + (size_t)2 * N_user, N_item, bufA, bufB, deg, dinv, rowptr, cursor, bsum, csr_src, stream);
}

// Round 4
// 774.223 us; speedup vs baseline: 1.4211x; 1.4211x over previous
//
#include <hip/hip_runtime.h>

#define CDIV(a,b) (((a)+(b)-1)/(b))
#define NPB 256   // nodes per bucket; bucket(d) = d >> 8

// ---------------- phase A0: global bucket histogram (LDS-staged) ----------------
__global__ __launch_bounds__(256) void hg_bhist(const int* __restrict__ dst, int* __restrict__ bhist,
                                                int E, int NB){
    extern __shared__ int sh[];                 // NB ints
    for (int i = threadIdx.x; i < NB; i += 256) sh[i] = 0;
    __syncthreads();
    const int e0 = blockIdx.x * 4096;
    const int eend = min(e0 + 4096, E);
    for (int e = e0 + threadIdx.x; e < eend; e += 256)
        atomicAdd(&sh[dst[e] >> 8], 1);
    __syncthreads();
    for (int i = threadIdx.x; i < NB; i += 256)
        if (sh[i]) atomicAdd(&bhist[i], sh[i]);
}

// ---------------- phase A-scan: exclusive scan of NB bucket counts (NB <= 1024) ----------------
__global__ __launch_bounds__(1024) void hg_bscan(const int* __restrict__ bhist, int* __restrict__ boff,
                                                 int NB, int E){
    __shared__ int sh[1024];
    const int t = threadIdx.x;
    const int v = (t < NB) ? bhist[t] : 0;
    sh[t] = v;
    __syncthreads();
    for (int off = 1; off < 1024; off <<= 1){
        int x = 0;
        if (t >= off) x = sh[t-off];
        __syncthreads();
        if (t >= off) sh[t] += x;
        __syncthreads();
    }
    if (t < NB) boff[t] = sh[t] - v;
    if (t == 0) boff[NB] = E;
}

// ---------------- phase A1: partition edges into buckets, packed src|(dst&255)<<24 ----------------
__global__ __launch_bounds__(256) void hg_partition(const int* __restrict__ src, const int* __restrict__ dst,
                                                    int* __restrict__ gcursor, unsigned int* __restrict__ bucketed,
                                                    int E, int NB){
    extern __shared__ int sh[];                 // lcnt[NB] + lbase[NB]
    int* lcnt  = sh;
    int* lbase = sh + NB;
    for (int i = threadIdx.x; i < NB; i += 256) lcnt[i] = 0;
    __syncthreads();
    const int e0 = blockIdx.x * 4096;
    const int eend = min(e0 + 4096, E);
    int lpos[16];
    #pragma unroll
    for (int j = 0; j < 16; ++j){
        const int e = e0 + threadIdx.x + j*256;
        lpos[j] = (e < eend) ? atomicAdd(&lcnt[dst[e] >> 8], 1) : 0;
    }
    __syncthreads();
    for (int i = threadIdx.x; i < NB; i += 256){
        const int c = lcnt[i];
        lbase[i] = c ? atomicAdd(&gcursor[i], c) : 0;
    }
    __syncthreads();
    #pragma unroll
    for (int j = 0; j < 16; ++j){
        const int e = e0 + threadIdx.x + j*256;
        if (e < eend){
            const int d = dst[e];
            const unsigned int word = (unsigned int)src[e] | ((unsigned int)(d & 255) << 24);
            bucketed[lbase[d >> 8] + lpos[j]] = word;
        }
    }
}

// ---------------- phase B: per-bucket deg/dinv/rowptr/counting-sort (one block per bucket) --------
__global__ __launch_bounds__(256) void hg_bucket_build(const unsigned int* __restrict__ bucketed,
                                                       const int* __restrict__ boff,
                                                       float* __restrict__ dinv, int* __restrict__ rowptr,
                                                       int* __restrict__ csr_src, int N, int E){
    __shared__ int hist[NPB];
    __shared__ int sc[NPB];
    __shared__ int cur[NPB];
    const int b   = blockIdx.x;
    const int t   = threadIdx.x;
    const int beg = boff[b], end = boff[b+1];
    hist[t] = 0;
    __syncthreads();
    for (int i = beg + t; i < end; i += 256)
        atomicAdd(&hist[bucketed[i] >> 24], 1);
    __syncthreads();
    const int d = hist[t];
    sc[t] = d;
    __syncthreads();
    for (int off = 1; off < 256; off <<= 1){
        int x = 0;
        if (t >= off) x = sc[t-off];
        __syncthreads();
        if (t >= off) sc[t] += x;
        __syncthreads();
    }
    const int excl = sc[t] - d;
    const int v = b*NPB + t;
    if (v < N){
        dinv[v]   = rsqrtf((float)(d + 1));     // +1 self-loop
        rowptr[v] = beg + excl;
    }
    if (b == 0 && t == 0) rowptr[N] = E;
    cur[t] = beg + excl;
    __syncthreads();
    for (int i = beg + t; i < end; i += 256){
        const unsigned int w = bucketed[i];
        const int p = atomicAdd(&cur[w >> 24], 1);
        csr_src[p] = (int)(w & 0x00FFFFFFu);
    }
}

// ---------------- fused GEMM: G[v][j] = (X[v,:] @ W[:,j]) * dinv[v] ----------------
// 64 rows/block; wave w handles 16 rows; lane = output col; x loads wave-uniform (broadcast)
template<int K>
__global__ __launch_bounds__(256) void hg_gemm_scaled(const float* __restrict__ X, const float* __restrict__ W,
                                                      const float* __restrict__ dinv, float* __restrict__ G, int N){
    __shared__ float Wl[K*64];
    for (int i = threadIdx.x; i < K*16; i += 256)
        ((float4*)Wl)[i] = ((const float4*)W)[i];
    __syncthreads();
    const int col  = threadIdx.x & 63;
    const int wid  = threadIdx.x >> 6;
    const int row0 = blockIdx.x * 64 + wid * 16;
    if (row0 >= N) return;

    if (row0 + 15 < N) {
        float acc[16];
        #pragma unroll
        for (int r = 0; r < 16; ++r) acc[r] = 0.f;
        const float* xb = X + (size_t)row0 * K;
        #pragma unroll 4
        for (int k = 0; k < K; k += 4) {
            const float w0 = Wl[(k+0)*64 + col];
            const float w1 = Wl[(k+1)*64 + col];
            const float w2 = Wl[(k+2)*64 + col];
            const float w3 = Wl[(k+3)*64 + col];
            #pragma unroll
            for (int r = 0; r < 16; ++r) {
                const float4 x = *(const float4*)(xb + (size_t)r*K + k);
                acc[r] = fmaf(x.w,w3, fmaf(x.z,w2, fmaf(x.y,w1, fmaf(x.x,w0, acc[r]))));
            }
        }
        #pragma unroll
        for (int r = 0; r < 16; ++r)
            G[(size_t)(row0+r)*64 + col] = acc[r] * dinv[row0+r];
    } else {
        for (int r = 0; r < 16; ++r) {
            const int row = row0 + r;
            if (row >= N) break;
            float acc = 0.f;
            const float* xr = X + (size_t)row * K;
            for (int k = 0; k < K; ++k) acc = fmaf(xr[k], Wl[k*64 + col], acc);
            G[(size_t)row*64 + col] = acc * dinv[row];
        }
    }
}

// ---------------- gather-aggregate + fused epilogue ----------------
__global__ __launch_bounds__(256) void hg_aggregate(const float* __restrict__ g, const int* __restrict__ csr_src,
                                                    const int* __restrict__ rowptr, const float* __restrict__ dinv,
                                                    const float* __restrict__ b, float* __restrict__ outp, int N){
    const int wid  = (blockIdx.x*256 + threadIdx.x) >> 6;
    const int lane = threadIdx.x & 63;
    if (wid >= N) return;
    const int beg = rowptr[wid];
    const int end = rowptr[wid+1];
    float acc = g[(size_t)wid*64 + lane];            // self-loop term
    float a0=0.f,a1=0.f,a2=0.f,a3=0.f,a4=0.f,a5=0.f,a6=0.f,a7=0.f;
    int i = beg;
    for (; i + 8 <= end; i += 8){
        const int s0 = csr_src[i+0]; const int s1 = csr_src[i+1];
        const int s2 = csr_src[i+2]; const int s3 = csr_src[i+3];
        const int s4 = csr_src[i+4]; const int s5 = csr_src[i+5];
        const int s6 = csr_src[i+6]; const int s7 = csr_src[i+7];
        a0 += g[(size_t)s0*64 + lane]; a1 += g[(size_t)s1*64 + lane];
        a2 += g[(size_t)s2*64 + lane]; a3 += g[(size_t)s3*64 + lane];
        a4 += g[(size_t)s4*64 + lane]; a5 += g[(size_t)s5*64 + lane];
        a6 += g[(size_t)s6*64 + lane]; a7 += g[(size_t)s7*64 + lane];
    }
    for (; i < end; ++i)
        a0 += g[(size_t)csr_src[i]*64 + lane];
    acc += ((a0+a1)+(a2+a3)) + ((a4+a5)+(a6+a7));
    outp[(size_t)wid*64 + lane] = fmaxf(fmaf(acc, dinv[wid], b[lane]), 0.f);
}

// ---------------- head: out[v][0:2] = H[v,:] @ Wl + bl ----------------
__global__ __launch_bounds__(256) void hg_head(const float* __restrict__ H, const float* __restrict__ Wl,
                                               const float* __restrict__ bl, float* __restrict__ outp, int N){
    int v = blockIdx.x*256 + threadIdx.x;
    if (v >= N) return;
    const float* h = H + (size_t)v*64;
    float a0 = bl[0], a1 = bl[1];
    #pragma unroll
    for (int k4 = 0; k4 < 16; ++k4) {
        const float4 x = *(const float4*)(h + k4*4);
        const float4 wA = *(const float4*)(Wl + k4*8 + 0);
        const float4 wB = *(const float4*)(Wl + k4*8 + 4);
        a0 = fmaf(x.x, wA.x, a0); a1 = fmaf(x.x, wA.y, a1);
        a0 = fmaf(x.y, wA.z, a0); a1 = fmaf(x.y, wA.w, a1);
        a0 = fmaf(x.z, wB.x, a0); a1 = fmaf(x.z, wB.y, a1);
        a0 = fmaf(x.w, wB.z, a0); a1 = fmaf(x.w, wB.w, a1);
    }
    float2 r; r.x = a0; r.y = a1;
    *(float2*)(outp + (size_t)v*2) = r;
}

// ---------------- orchestration ----------------
static void run_type(const float* x, const int* ei, int E,
                     const float* W1, const float* b1,
                     const float* W2, const float* b2,
                     const float* Wl, const float* bl,
                     float* out, int N,
                     float* bufA, float* bufB, float* dinv,
                     int* rowptr, int* csr_src, unsigned int* bucketed,
                     int* bhist, int* boff, int* gcursor,
                     hipStream_t stream){
    const int* src = ei;
    const int* dst = ei + E;
    const int NB = CDIV(N, NPB);

    // CSR build (bucketed; reused by both layers)
    hipMemsetAsync(bhist, 0, (size_t)NB * sizeof(int), stream);
    hg_bhist<<<CDIV(E,4096), 256, NB*sizeof(int), stream>>>(dst, bhist, E, NB);
    hg_bscan<<<1, 1024, 0, stream>>>(bhist, boff, NB, E);
    hipMemcpyAsync(gcursor, boff, (size_t)NB * sizeof(int), hipMemcpyDeviceToDevice, stream);
    hg_partition<<<CDIV(E,4096), 256, 2*NB*sizeof(int), stream>>>(src, dst, gcursor, bucketed, E, NB);
    hg_bucket_build<<<NB, 256, 0, stream>>>(bucketed, boff, dinv, rowptr, csr_src, N, E);

    // layer 1
    hg_gemm_scaled<128><<<CDIV(N,64), 256, 0, stream>>>(x, W1, dinv, bufA, N);
    hg_aggregate<<<CDIV(N,4), 256, 0, stream>>>(bufA, csr_src, rowptr, dinv, b1, bufB, N);

    // layer 2
    hg_gemm_scaled<64><<<CDIV(N,64), 256, 0, stream>>>(bufB, W2, dinv, bufA, N);
    hg_aggregate<<<CDIV(N,4), 256, 0, stream>>>(bufA, csr_src, rowptr, dinv, b2, bufB, N);

    // head
    hg_head<<<CDIV(N,256), 256, 0, stream>>>(bufB, Wl, bl, out, N);
}

extern "C" void kernel_launch(void* const* d_in, const int* in_sizes, int n_in,
                              void* d_out, int out_size, void* d_ws, size_t ws_size,
                              hipStream_t stream) {
    const float* x_user = (const float*)d_in[0];
    const float* x_item = (const float*)d_in[1];
    const int*  ei_user = (const int*)d_in[2];
    const int*  ei_item = (const int*)d_in[3];
    const float* W1_user = (const float*)d_in[4];
    const float* b1_user = (const float*)d_in[5];
    const float* W1_item = (const float*)d_in[6];
    const float* b1_item = (const float*)d_in[7];
    const float* W2_user = (const float*)d_in[8];
    const float* b2_user = (const float*)d_in[9];
    const float* W2_item = (const float*)d_in[10];
    const float* b2_item = (const float*)d_in[11];
    const float* Wl_user = (const float*)d_in[12];
    const float* bl_user = (const float*)d_in[13];
    const float* Wl_item = (const float*)d_in[14];
    const float* bl_item = (const float*)d_in[15];

    const int N_user = in_sizes[0] / 128;
    const int N_item = in_sizes[1] / 128;
    const int E_user = in_sizes[2] / 2;
    const int E_item = in_sizes[3] / 2;
    const int NMAX = (N_user > N_item) ? N_user : N_item;
    const int EMAX = (E_user > E_item) ? E_user : E_item;
    const int NBMAX = CDIV(NMAX, NPB);

    char* w = (char*)d_ws;
    float* bufA    = (float*)w;        w += (size_t)NMAX * 64 * sizeof(float);
    float* bufB    = (float*)w;        w += (size_t)NMAX * 64 * sizeof(float);
    float* dinv    = (float*)w;        w += (size_t)NMAX * sizeof(float);
    int*   rowptr  = (int*)w;          w += ((size_t)NMAX + 1) * sizeof(int);
    int*   csr_src = (int*)w;          w += (size_t)EMAX * sizeof(int);
    unsigned int* bucketed = (unsigned int*)w;  w += (size_t)EMAX * sizeof(int);
    int*   bhist   = (int*)w;          w += (size_t)NBMAX * sizeof(int);
    int*   boff    = (int*)w;          w += ((size_t)NBMAX + 1) * sizeof(int);
    int*   gcursor = (int*)w;          w += (size_t)NBMAX * sizeof(int);

    float* out = (float*)d_out;

    run_type(x_user, ei_user, E_user, W1_user, b1_user, W2_user, b2_user, Wl_user, bl_user,
             out, N_user, bufA, bufB, dinv, rowptr, csr_src, bucketed, bhist, boff, gcursor, stream);
    run_type(x_item, ei_item, E_item, W1_item, b1_item, W2_item, b2_item, Wl_item, bl_item,
             out + (size_t)2 * N_user, N_item, bufA, bufB, dinv, rowptr, csr_src, bucketed, bhist, boff, gcursor, stream);
}

// Round 5
// 504.249 us; speedup vs baseline: 2.1819x; 1.5354x over previous
//
#include <hip/hip_runtime.h>

#define CDIV(a,b) (((a)+(b)-1)/(b))
#define NPB 256   // nodes per bucket; bucket(d) = d >> 8

typedef __attribute__((ext_vector_type(8))) short bf16x8;
typedef __attribute__((ext_vector_type(4))) float f32x4;

__device__ __forceinline__ unsigned short f2bf(float x){
    unsigned int u = __float_as_uint(x);
    unsigned int r = u + 0x7FFFu + ((u >> 16) & 1u);   // RNE
    return (unsigned short)(r >> 16);
}
__device__ __forceinline__ float bf2f(unsigned short h){
    return __uint_as_float(((unsigned int)h) << 16);
}

// ---------------- phase A0: global bucket histogram (LDS-staged) ----------------
__global__ __launch_bounds__(256) void hg_bhist(const int* __restrict__ dst, int* __restrict__ bhist,
                                                int E, int NB){
    extern __shared__ int sh[];                 // NB ints
    for (int i = threadIdx.x; i < NB; i += 256) sh[i] = 0;
    __syncthreads();
    const int e0 = blockIdx.x * 4096;
    const int eend = min(e0 + 4096, E);
    for (int e = e0 + threadIdx.x; e < eend; e += 256)
        atomicAdd(&sh[dst[e] >> 8], 1);
    __syncthreads();
    for (int i = threadIdx.x; i < NB; i += 256)
        if (sh[i]) atomicAdd(&bhist[i], sh[i]);
}

// ---------------- phase A-scan: exclusive scan of NB bucket counts ----------------
__global__ __launch_bounds__(1024) void hg_bscan(const int* __restrict__ bhist, int* __restrict__ boff,
                                                 int NB, int E){
    __shared__ int sh[1024];
    const int t = threadIdx.x;
    const int v = (t < NB) ? bhist[t] : 0;
    sh[t] = v;
    __syncthreads();
    for (int off = 1; off < 1024; off <<= 1){
        int x = 0;
        if (t >= off) x = sh[t-off];
        __syncthreads();
        if (t >= off) sh[t] += x;
        __syncthreads();
    }
    if (t < NB) boff[t] = sh[t] - v;
    if (t == 0) boff[NB] = E;
}

// ---------------- phase A1: partition edges into buckets, packed src|(dst&255)<<24 ----------------
__global__ __launch_bounds__(256) void hg_partition(const int* __restrict__ src, const int* __restrict__ dst,
                                                    int* __restrict__ gcursor, unsigned int* __restrict__ bucketed,
                                                    int E, int NB){
    extern __shared__ int sh[];                 // lcnt[NB] + lbase[NB]
    int* lcnt  = sh;
    int* lbase = sh + NB;
    for (int i = threadIdx.x; i < NB; i += 256) lcnt[i] = 0;
    __syncthreads();
    const int e0 = blockIdx.x * 4096;
    const int eend = min(e0 + 4096, E);
    int lpos[16];
    #pragma unroll
    for (int j = 0; j < 16; ++j){
        const int e = e0 + threadIdx.x + j*256;
        lpos[j] = (e < eend) ? atomicAdd(&lcnt[dst[e] >> 8], 1) : 0;
    }
    __syncthreads();
    for (int i = threadIdx.x; i < NB; i += 256){
        const int c = lcnt[i];
        lbase[i] = c ? atomicAdd(&gcursor[i], c) : 0;
    }
    __syncthreads();
    #pragma unroll
    for (int j = 0; j < 16; ++j){
        const int e = e0 + threadIdx.x + j*256;
        if (e < eend){
            const int d = dst[e];
            const unsigned int word = (unsigned int)src[e] | ((unsigned int)(d & 255) << 24);
            bucketed[lbase[d >> 8] + lpos[j]] = word;
        }
    }
}

// ---------------- phase B: per-bucket deg/dinv/rowptr/counting-sort ----------------
__global__ __launch_bounds__(256) void hg_bucket_build(const unsigned int* __restrict__ bucketed,
                                                       const int* __restrict__ boff,
                                                       float* __restrict__ dinv, int* __restrict__ rowptr,
                                                       int* __restrict__ csr_src, int N, int E){
    __shared__ int hist[NPB];
    __shared__ int sc[NPB];
    __shared__ int cur[NPB];
    const int b   = blockIdx.x;
    const int t   = threadIdx.x;
    const int beg = boff[b], end = boff[b+1];
    hist[t] = 0;
    __syncthreads();
    for (int i = beg + t; i < end; i += 256)
        atomicAdd(&hist[bucketed[i] >> 24], 1);
    __syncthreads();
    const int d = hist[t];
    sc[t] = d;
    __syncthreads();
    for (int off = 1; off < 256; off <<= 1){
        int x = 0;
        if (t >= off) x = sc[t-off];
        __syncthreads();
        if (t >= off) sc[t] += x;
        __syncthreads();
    }
    const int excl = sc[t] - d;
    const int v = b*NPB + t;
    if (v < N){
        dinv[v]   = rsqrtf((float)(d + 1));     // +1 self-loop
        rowptr[v] = beg + excl;
    }
    if (b == 0 && t == 0) rowptr[N] = E;
    cur[t] = beg + excl;
    __syncthreads();
    for (int i = beg + t; i < end; i += 256){
        const unsigned int w = bucketed[i];
        const int p = atomicAdd(&cur[w >> 24], 1);
        csr_src[p] = (int)(w & 0x00FFFFFFu);
    }
}

// ---------------- W split+fragment-order prep ----------------
// slot = ((ks*4 + ct)*64 + lane); element j of slot = W[ks*32 + (lane>>4)*8 + j][ct*16 + (lane&15)]
__global__ __launch_bounds__(256) void hg_wsplit(const float* __restrict__ W,
                                                 unsigned short* __restrict__ Bhi,
                                                 unsigned short* __restrict__ Blo, int K){
    const int slot = blockIdx.x*256 + threadIdx.x;
    const int total = (K/32)*4*64;
    if (slot >= total) return;
    const int l  = slot & 63;
    const int ct = (slot >> 6) & 3;
    const int ks = slot >> 8;
    const int kb = ks*32 + (l >> 4)*8;
    const int c  = ct*16 + (l & 15);
    #pragma unroll
    for (int j = 0; j < 8; ++j){
        const float w = W[(size_t)(kb + j)*64 + c];
        const unsigned short h = f2bf(w);
        Bhi[(size_t)slot*8 + j] = h;
        Blo[(size_t)slot*8 + j] = f2bf(w - bf2f(h));
    }
}

// ---------------- MFMA GEMM: G[v][j] = (X[v,:] @ W[:,j]) * dinv[v] ----------------
// block = 256 = 4 waves; wave w -> rows [blk*64 + w*16, +16); 4 col-tiles of 16.
// split-bf16: acc += Ahi*Bhi + Alo*Bhi + Ahi*Blo
template<int K>
__global__ __launch_bounds__(256) void hg_gemm_mfma(const float* __restrict__ X,
                                                    const unsigned short* __restrict__ Bhi,
                                                    const unsigned short* __restrict__ Blo,
                                                    const float* __restrict__ dinv,
                                                    float* __restrict__ G, int N){
    const int l = threadIdx.x & 63;
    const int w = threadIdx.x >> 6;
    const int row0 = blockIdx.x*64 + w*16;
    if (row0 >= N) return;

    f32x4 acc[4];
    #pragma unroll
    for (int ct = 0; ct < 4; ++ct) acc[ct] = (f32x4){0.f,0.f,0.f,0.f};

    const int rA = row0 + (l & 15);         // row this lane supplies to the A-fragment
    const int kg = (l >> 4) * 8;            // k-offset of this lane's 8 elements
    const bool rowok = (rA < N);
    const float* xrow = X + (size_t)rA * K;

    #pragma unroll
    for (int ks = 0; ks < K/32; ++ks){
        float xv[8];
        if (rowok){
            const float4 a = *(const float4*)(xrow + ks*32 + kg);
            const float4 b = *(const float4*)(xrow + ks*32 + kg + 4);
            xv[0]=a.x; xv[1]=a.y; xv[2]=a.z; xv[3]=a.w;
            xv[4]=b.x; xv[5]=b.y; xv[6]=b.z; xv[7]=b.w;
        } else {
            #pragma unroll
            for (int j = 0; j < 8; ++j) xv[j] = 0.f;
        }
        bf16x8 ahi, alo;
        #pragma unroll
        for (int j = 0; j < 8; ++j){
            const unsigned short h = f2bf(xv[j]);
            ahi[j] = (short)h;
            alo[j] = (short)f2bf(xv[j] - bf2f(h));
        }
        #pragma unroll
        for (int ct = 0; ct < 4; ++ct){
            const bf16x8 bhi = *(const bf16x8*)(Bhi + ((size_t)(ks*4 + ct)*64 + l)*8);
            const bf16x8 blo = *(const bf16x8*)(Blo + ((size_t)(ks*4 + ct)*64 + l)*8);
            acc[ct] = __builtin_amdgcn_mfma_f32_16x16x32_bf16(ahi, bhi, acc[ct], 0, 0, 0);
            acc[ct] = __builtin_amdgcn_mfma_f32_16x16x32_bf16(alo, bhi, acc[ct], 0, 0, 0);
            acc[ct] = __builtin_amdgcn_mfma_f32_16x16x32_bf16(ahi, blo, acc[ct], 0, 0, 0);
        }
    }

    // D: lane l, reg r -> row (l>>4)*4 + r, col l&15 (within 16x16 tile)
    const int orow0 = row0 + (l >> 4)*4;
    const int ocol  = l & 15;
    #pragma unroll
    for (int r = 0; r < 4; ++r){
        const int orow = orow0 + r;
        if (orow < N){
            const float dv = dinv[orow];
            #pragma unroll
            for (int ct = 0; ct < 4; ++ct)
                G[(size_t)orow*64 + ct*16 + ocol] = acc[ct][r] * dv;
        }
    }
}

// ---------------- gather-aggregate + fused epilogue ----------------
__global__ __launch_bounds__(256) void hg_aggregate(const float* __restrict__ g, const int* __restrict__ csr_src,
                                                    const int* __restrict__ rowptr, const float* __restrict__ dinv,
                                                    const float* __restrict__ b, float* __restrict__ outp, int N){
    const int wid  = (blockIdx.x*256 + threadIdx.x) >> 6;
    const int lane = threadIdx.x & 63;
    if (wid >= N) return;
    const int beg = rowptr[wid];
    const int end = rowptr[wid+1];
    float acc = g[(size_t)wid*64 + lane];            // self-loop term
    float a0=0.f,a1=0.f,a2=0.f,a3=0.f,a4=0.f,a5=0.f,a6=0.f,a7=0.f;
    int i = beg;
    for (; i + 8 <= end; i += 8){
        const int s0 = csr_src[i+0]; const int s1 = csr_src[i+1];
        const int s2 = csr_src[i+2]; const int s3 = csr_src[i+3];
        const int s4 = csr_src[i+4]; const int s5 = csr_src[i+5];
        const int s6 = csr_src[i+6]; const int s7 = csr_src[i+7];
        a0 += g[(size_t)s0*64 + lane]; a1 += g[(size_t)s1*64 + lane];
        a2 += g[(size_t)s2*64 + lane]; a3 += g[(size_t)s3*64 + lane];
        a4 += g[(size_t)s4*64 + lane]; a5 += g[(size_t)s5*64 + lane];
        a6 += g[(size_t)s6*64 + lane]; a7 += g[(size_t)s7*64 + lane];
    }
    for (; i < end; ++i)
        a0 += g[(size_t)csr_src[i]*64 + lane];
    acc += ((a0+a1)+(a2+a3)) + ((a4+a5)+(a6+a7));
    outp[(size_t)wid*64 + lane] = fmaxf(fmaf(acc, dinv[wid], b[lane]), 0.f);
}

// ---------------- head: out[v][0:2] = H[v,:] @ Wl + bl ----------------
__global__ __launch_bounds__(256) void hg_head(const float* __restrict__ H, const float* __restrict__ Wl,
                                               const float* __restrict__ bl, float* __restrict__ outp, int N){
    int v = blockIdx.x*256 + threadIdx.x;
    if (v >= N) return;
    const float* h = H + (size_t)v*64;
    float a0 = bl[0], a1 = bl[1];
    #pragma unroll
    for (int k4 = 0; k4 < 16; ++k4) {
        const float4 x = *(const float4*)(h + k4*4);
        const float4 wA = *(const float4*)(Wl + k4*8 + 0);
        const float4 wB = *(const float4*)(Wl + k4*8 + 4);
        a0 = fmaf(x.x, wA.x, a0); a1 = fmaf(x.x, wA.y, a1);
        a0 = fmaf(x.y, wA.z, a0); a1 = fmaf(x.y, wA.w, a1);
        a0 = fmaf(x.z, wB.x, a0); a1 = fmaf(x.z, wB.y, a1);
        a0 = fmaf(x.w, wB.z, a0); a1 = fmaf(x.w, wB.w, a1);
    }
    float2 r; r.x = a0; r.y = a1;
    *(float2*)(outp + (size_t)v*2) = r;
}

// ---------------- orchestration ----------------
static void run_type(const float* x, const int* ei, int E,
                     const float* W1, const float* b1,
                     const float* W2, const float* b2,
                     const float* Wl, const float* bl,
                     float* out, int N,
                     float* bufA, float* bufB, float* dinv,
                     int* rowptr, int* csr_src, unsigned int* bucketed,
                     int* bhist, int* boff, int* gcursor,
                     unsigned short* Bhi, unsigned short* Blo,
                     hipStream_t stream){
    const int* src = ei;
    const int* dst = ei + E;
    const int NB = CDIV(N, NPB);

    // CSR build (bucketed; reused by both layers)
    hipMemsetAsync(bhist, 0, (size_t)NB * sizeof(int), stream);
    hg_bhist<<<CDIV(E,4096), 256, NB*sizeof(int), stream>>>(dst, bhist, E, NB);
    hg_bscan<<<1, 1024, 0, stream>>>(bhist, boff, NB, E);
    hipMemcpyAsync(gcursor, boff, (size_t)NB * sizeof(int), hipMemcpyDeviceToDevice, stream);
    hg_partition<<<CDIV(E,4096), 256, 2*NB*sizeof(int), stream>>>(src, dst, gcursor, bucketed, E, NB);
    hg_bucket_build<<<NB, 256, 0, stream>>>(bucketed, boff, dinv, rowptr, csr_src, N, E);

    // layer 1 (K=128)
    hg_wsplit<<<CDIV(4*4*64,256), 256, 0, stream>>>(W1, Bhi, Blo, 128);
    hg_gemm_mfma<128><<<CDIV(N,64), 256, 0, stream>>>(x, Bhi, Blo, dinv, bufA, N);
    hg_aggregate<<<CDIV(N,4), 256, 0, stream>>>(bufA, csr_src, rowptr, dinv, b1, bufB, N);

    // layer 2 (K=64)
    hg_wsplit<<<CDIV(2*4*64,256), 256, 0, stream>>>(W2, Bhi, Blo, 64);
    hg_gemm_mfma<64><<<CDIV(N,64), 256, 0, stream>>>(bufB, Bhi, Blo, dinv, bufA, N);
    hg_aggregate<<<CDIV(N,4), 256, 0, stream>>>(bufA, csr_src, rowptr, dinv, b2, bufB, N);

    // head
    hg_head<<<CDIV(N,256), 256, 0, stream>>>(bufB, Wl, bl, out, N);
}

extern "C" void kernel_launch(void* const* d_in, const int* in_sizes, int n_in,
                              void* d_out, int out_size, void* d_ws, size_t ws_size,
                              hipStream_t stream) {
    const float* x_user = (const float*)d_in[0];
    const float* x_item = (const float*)d_in[1];
    const int*  ei_user = (const int*)d_in[2];
    const int*  ei_item = (const int*)d_in[3];
    const float* W1_user = (const float*)d_in[4];
    const float* b1_user = (const float*)d_in[5];
    const float* W1_item = (const float*)d_in[6];
    const float* b1_item = (const float*)d_in[7];
    const float* W2_user = (const float*)d_in[8];
    const float* b2_user = (const float*)d_in[9];
    const float* W2_item = (const float*)d_in[10];
    const float* b2_item = (const float*)d_in[11];
    const float* Wl_user = (const float*)d_in[12];
    const float* bl_user = (const float*)d_in[13];
    const float* Wl_item = (const float*)d_in[14];
    const float* bl_item = (const float*)d_in[15];

    const int N_user = in_sizes[0] / 128;
    const int N_item = in_sizes[1] / 128;
    const int E_user = in_sizes[2] / 2;
    const int E_item = in_sizes[3] / 2;
    const int NMAX = (N_user > N_item) ? N_user : N_item;
    const int EMAX = (E_user > E_item) ? E_user : E_item;
    const int NBMAX = CDIV(NMAX, NPB);

    char* w = (char*)d_ws;
    float* bufA    = (float*)w;        w += (size_t)NMAX * 64 * sizeof(float);
    float* bufB    = (float*)w;        w += (size_t)NMAX * 64 * sizeof(float);
    float* dinv    = (float*)w;        w += (size_t)NMAX * sizeof(float);
    int*   rowptr  = (int*)w;          w += ((size_t)NMAX + 1) * sizeof(int);
    int*   csr_src = (int*)w;          w += (size_t)EMAX * sizeof(int);
    unsigned int* bucketed = (unsigned int*)w;  w += (size_t)EMAX * sizeof(int);
    int*   bhist   = (int*)w;          w += (size_t)NBMAX * sizeof(int);
    int*   boff    = (int*)w;          w += ((size_t)NBMAX + 1) * sizeof(int);
    int*   gcursor = (int*)w;          w += (size_t)NBMAX * sizeof(int);
    unsigned short* Bhi = (unsigned short*)w;   w += (size_t)128 * 64 * sizeof(unsigned short);
    unsigned short* Blo = (unsigned short*)w;   w += (size_t)128 * 64 * sizeof(unsigned short);

    float* out = (float*)d_out;

    run_type(x_user, ei_user, E_user, W1_user, b1_user, W2_user, b2_user, Wl_user, bl_user,
             out, N_user, bufA, bufB, dinv, rowptr, csr_src, bucketed, bhist, boff, gcursor,
             Bhi, Blo, stream);
    run_type(x_item, ei_item, E_item, W1_item, b1_item, W2_item, b2_item, Wl_item, bl_item,
             out + (size_t)2 * N_user, N_item, bufA, bufB, dinv, rowptr, csr_src, bucketed, bhist, boff, gcursor,
             Bhi, Blo, stream);
}

// Round 7
// 458.610 us; speedup vs baseline: 2.3991x; 1.0995x over previous
//
#include <hip/hip_runtime.h>

#define CDIV(a,b) (((a)+(b)-1)/(b))
#define NPB 256   // nodes per bucket; bucket(d) = d >> 8

typedef __attribute__((ext_vector_type(8))) short bf16x8;
typedef __attribute__((ext_vector_type(4))) float f32x4;

__device__ __forceinline__ unsigned short f2bf(float x){
    unsigned int u = __float_as_uint(x);
    unsigned int r = u + 0x7FFFu + ((u >> 16) & 1u);   // RNE
    return (unsigned short)(r >> 16);
}
__device__ __forceinline__ float bf2f(unsigned short h){
    return __uint_as_float(((unsigned int)h) << 16);
}

// ---------------- phase A0: global bucket histogram (LDS-staged) ----------------
__global__ __launch_bounds__(256) void hg_bhist(const int* __restrict__ dst, int* __restrict__ bhist,
                                                int E, int NB){
    extern __shared__ int sh[];                 // NB ints
    for (int i = threadIdx.x; i < NB; i += 256) sh[i] = 0;
    __syncthreads();
    const int e0 = blockIdx.x * 4096;
    const int eend = min(e0 + 4096, E);
    for (int e = e0 + threadIdx.x; e < eend; e += 256)
        atomicAdd(&sh[dst[e] >> 8], 1);
    __syncthreads();
    for (int i = threadIdx.x; i < NB; i += 256)
        if (sh[i]) atomicAdd(&bhist[i], sh[i]);
}

// ---------------- phase A-scan: exclusive scan of NB bucket counts ----------------
__global__ __launch_bounds__(1024) void hg_bscan(const int* __restrict__ bhist, int* __restrict__ boff,
                                                 int NB, int E){
    __shared__ int sh[1024];
    const int t = threadIdx.x;
    const int v = (t < NB) ? bhist[t] : 0;
    sh[t] = v;
    __syncthreads();
    for (int off = 1; off < 1024; off <<= 1){
        int x = 0;
        if (t >= off) x = sh[t-off];
        __syncthreads();
        if (t >= off) sh[t] += x;
        __syncthreads();
    }
    if (t < NB) boff[t] = sh[t] - v;
    if (t == 0) boff[NB] = E;
}

// ---------------- phase A1: partition edges into buckets, packed src|(dst&255)<<24 ----------------
__global__ __launch_bounds__(256) void hg_partition(const int* __restrict__ src, const int* __restrict__ dst,
                                                    int* __restrict__ gcursor, unsigned int* __restrict__ bucketed,
                                                    int E, int NB){
    extern __shared__ int sh[];                 // lcnt[NB] + lbase[NB]
    int* lcnt  = sh;
    int* lbase = sh + NB;
    for (int i = threadIdx.x; i < NB; i += 256) lcnt[i] = 0;
    __syncthreads();
    const int e0 = blockIdx.x * 4096;
    const int eend = min(e0 + 4096, E);
    int lpos[16];
    #pragma unroll
    for (int j = 0; j < 16; ++j){
        const int e = e0 + threadIdx.x + j*256;
        lpos[j] = (e < eend) ? atomicAdd(&lcnt[dst[e] >> 8], 1) : 0;
    }
    __syncthreads();
    for (int i = threadIdx.x; i < NB; i += 256){
        const int c = lcnt[i];
        lbase[i] = c ? atomicAdd(&gcursor[i], c) : 0;
    }
    __syncthreads();
    #pragma unroll
    for (int j = 0; j < 16; ++j){
        const int e = e0 + threadIdx.x + j*256;
        if (e < eend){
            const int d = dst[e];
            const unsigned int word = (unsigned int)src[e] | ((unsigned int)(d & 255) << 24);
            bucketed[lbase[d >> 8] + lpos[j]] = word;
        }
    }
}

// ---------------- phase B: per-bucket deg/dinv/rowptr/counting-sort ----------------
__global__ __launch_bounds__(256) void hg_bucket_build(const unsigned int* __restrict__ bucketed,
                                                       const int* __restrict__ boff,
                                                       float* __restrict__ dinv, int* __restrict__ rowptr,
                                                       int* __restrict__ csr_src, int N, int E){
    __shared__ int hist[NPB];
    __shared__ int sc[NPB];
    __shared__ int cur[NPB];
    const int b   = blockIdx.x;
    const int t   = threadIdx.x;
    const int beg = boff[b], end = boff[b+1];
    hist[t] = 0;
    __syncthreads();
    for (int i = beg + t; i < end; i += 256)
        atomicAdd(&hist[bucketed[i] >> 24], 1);
    __syncthreads();
    const int d = hist[t];
    sc[t] = d;
    __syncthreads();
    for (int off = 1; off < 256; off <<= 1){
        int x = 0;
        if (t >= off) x = sc[t-off];
        __syncthreads();
        if (t >= off) sc[t] += x;
        __syncthreads();
    }
    const int excl = sc[t] - d;
    const int v = b*NPB + t;
    if (v < N){
        dinv[v]   = rsqrtf((float)(d + 1));     // +1 self-loop
        rowptr[v] = beg + excl;
    }
    if (b == 0 && t == 0) rowptr[N] = E;
    cur[t] = beg + excl;
    __syncthreads();
    for (int i = beg + t; i < end; i += 256){
        const unsigned int w = bucketed[i];
        const int p = atomicAdd(&cur[w >> 24], 1);
        csr_src[p] = (int)(w & 0x00FFFFFFu);
    }
}

// ---------------- W split+fragment-order prep ----------------
__global__ __launch_bounds__(256) void hg_wsplit(const float* __restrict__ W,
                                                 unsigned short* __restrict__ Bhi,
                                                 unsigned short* __restrict__ Blo, int K){
    const int slot = blockIdx.x*256 + threadIdx.x;
    const int total = (K/32)*4*64;
    if (slot >= total) return;
    const int l  = slot & 63;
    const int ct = (slot >> 6) & 3;
    const int ks = slot >> 8;
    const int kb = ks*32 + (l >> 4)*8;
    const int c  = ct*16 + (l & 15);
    #pragma unroll
    for (int j = 0; j < 8; ++j){
        const float w = W[(size_t)(kb + j)*64 + c];
        const unsigned short h = f2bf(w);
        Bhi[(size_t)slot*8 + j] = h;
        Blo[(size_t)slot*8 + j] = f2bf(w - bf2f(h));
    }
}

// ---------------- MFMA GEMM: G[v][j] = (X[v,:] @ W[:,j]) * dinv[v] ----------------
template<int K>
__global__ __launch_bounds__(256) void hg_gemm_mfma(const float* __restrict__ X,
                                                    const unsigned short* __restrict__ Bhi,
                                                    const unsigned short* __restrict__ Blo,
                                                    const float* __restrict__ dinv,
                                                    float* __restrict__ G, int N){
    const int l = threadIdx.x & 63;
    const int w = threadIdx.x >> 6;
    const int row0 = blockIdx.x*64 + w*16;
    if (row0 >= N) return;

    f32x4 acc[4];
    #pragma unroll
    for (int ct = 0; ct < 4; ++ct) acc[ct] = (f32x4){0.f,0.f,0.f,0.f};

    const int rA = row0 + (l & 15);
    const int kg = (l >> 4) * 8;
    const bool rowok = (rA < N);
    const float* xrow = X + (size_t)rA * K;

    #pragma unroll
    for (int ks = 0; ks < K/32; ++ks){
        float xv[8];
        if (rowok){
            const float4 a = *(const float4*)(xrow + ks*32 + kg);
            const float4 b = *(const float4*)(xrow + ks*32 + kg + 4);
            xv[0]=a.x; xv[1]=a.y; xv[2]=a.z; xv[3]=a.w;
            xv[4]=b.x; xv[5]=b.y; xv[6]=b.z; xv[7]=b.w;
        } else {
            #pragma unroll
            for (int j = 0; j < 8; ++j) xv[j] = 0.f;
        }
        bf16x8 ahi, alo;
        #pragma unroll
        for (int j = 0; j < 8; ++j){
            const unsigned short h = f2bf(xv[j]);
            ahi[j] = (short)h;
            alo[j] = (short)f2bf(xv[j] - bf2f(h));
        }
        #pragma unroll
        for (int ct = 0; ct < 4; ++ct){
            const bf16x8 bhi = *(const bf16x8*)(Bhi + ((size_t)(ks*4 + ct)*64 + l)*8);
            const bf16x8 blo = *(const bf16x8*)(Blo + ((size_t)(ks*4 + ct)*64 + l)*8);
            acc[ct] = __builtin_amdgcn_mfma_f32_16x16x32_bf16(ahi, bhi, acc[ct], 0, 0, 0);
            acc[ct] = __builtin_amdgcn_mfma_f32_16x16x32_bf16(alo, bhi, acc[ct], 0, 0, 0);
            acc[ct] = __builtin_amdgcn_mfma_f32_16x16x32_bf16(ahi, blo, acc[ct], 0, 0, 0);
        }
    }

    const int orow0 = row0 + (l >> 4)*4;
    const int ocol  = l & 15;
    #pragma unroll
    for (int r = 0; r < 4; ++r){
        const int orow = orow0 + r;
        if (orow < N){
            const float dv = dinv[orow];
            #pragma unroll
            for (int ct = 0; ct < 4; ++ct)
                G[(size_t)orow*64 + ct*16 + ocol] = acc[ct][r] * dv;
        }
    }
}

// ---------------- gather-aggregate: 4 nodes/wave, 16 lanes x float4 per node ----------------
// out = relu((sum_in g[s] + g[v]) * dinv[v] + b); 1 KB of gather payload per VMEM instruction
__global__ __launch_bounds__(256) void hg_aggregate4(const float* __restrict__ g, const int* __restrict__ csr_src,
                                                     const int* __restrict__ rowptr, const float* __restrict__ dinv,
                                                     const float* __restrict__ b, float* __restrict__ outp, int N){
    const int wave = (blockIdx.x*256 + threadIdx.x) >> 6;
    const int sub  = (threadIdx.x >> 4) & 3;      // node slot within wave
    const int c4   = (threadIdx.x & 15) << 2;     // float chunk offset (0,4,...,60)
    const int v    = wave*4 + sub;
    const bool ok  = (v < N);

    int beg = 0, cnt = 0;
    if (ok){ beg = rowptr[v]; cnt = rowptr[v+1] - beg; }

    f32x4 self = (f32x4){0.f,0.f,0.f,0.f};
    if (ok) self = *(const f32x4*)(g + (size_t)v*64 + c4);

    f32x4 A0 = (f32x4){0,0,0,0}, A1 = A0, A2 = A0, A3 = A0;
    f32x4 A4 = A0, A5 = A0, A6 = A0, A7 = A0;

    int i = 0;
    for (; i + 8 <= cnt; i += 8){
        const int s0 = csr_src[beg+i+0]; const int s1 = csr_src[beg+i+1];
        const int s2 = csr_src[beg+i+2]; const int s3 = csr_src[beg+i+3];
        const int s4 = csr_src[beg+i+4]; const int s5 = csr_src[beg+i+5];
        const int s6 = csr_src[beg+i+6]; const int s7 = csr_src[beg+i+7];
        A0 += *(const f32x4*)(g + (size_t)s0*64 + c4);
        A1 += *(const f32x4*)(g + (size_t)s1*64 + c4);
        A2 += *(const f32x4*)(g + (size_t)s2*64 + c4);
        A3 += *(const f32x4*)(g + (size_t)s3*64 + c4);
        A4 += *(const f32x4*)(g + (size_t)s4*64 + c4);
        A5 += *(const f32x4*)(g + (size_t)s5*64 + c4);
        A6 += *(const f32x4*)(g + (size_t)s6*64 + c4);
        A7 += *(const f32x4*)(g + (size_t)s7*64 + c4);
    }
    for (; i + 4 <= cnt; i += 4){
        const int s0 = csr_src[beg+i+0]; const int s1 = csr_src[beg+i+1];
        const int s2 = csr_src[beg+i+2]; const int s3 = csr_src[beg+i+3];
        A0 += *(const f32x4*)(g + (size_t)s0*64 + c4);
        A1 += *(const f32x4*)(g + (size_t)s1*64 + c4);
        A2 += *(const f32x4*)(g + (size_t)s2*64 + c4);
        A3 += *(const f32x4*)(g + (size_t)s3*64 + c4);
    }
    for (; i < cnt; ++i)
        A0 += *(const f32x4*)(g + (size_t)csr_src[beg+i]*64 + c4);

    if (ok){
        const f32x4 acc = self + ((A0+A1)+(A2+A3)) + ((A4+A5)+(A6+A7));
        const float dv = dinv[v];
        const f32x4 bb = *(const f32x4*)(b + c4);
        f32x4 r;
        r.x = fmaxf(fmaf(acc.x, dv, bb.x), 0.f);
        r.y = fmaxf(fmaf(acc.y, dv, bb.y), 0.f);
        r.z = fmaxf(fmaf(acc.z, dv, bb.z), 0.f);
        r.w = fmaxf(fmaf(acc.w, dv, bb.w), 0.f);
        *(f32x4*)(outp + (size_t)v*64 + c4) = r;
    }
}

// ---------------- head: out[v][0:2] = H[v,:] @ Wl + bl ----------------
__global__ __launch_bounds__(256) void hg_head(const float* __restrict__ H, const float* __restrict__ Wl,
                                               const float* __restrict__ bl, float* __restrict__ outp, int N){
    int v = blockIdx.x*256 + threadIdx.x;
    if (v >= N) return;
    const float* h = H + (size_t)v*64;
    float a0 = bl[0], a1 = bl[1];
    #pragma unroll
    for (int k4 = 0; k4 < 16; ++k4) {
        const float4 x = *(const float4*)(h + k4*4);
        const float4 wA = *(const float4*)(Wl + k4*8 + 0);
        const float4 wB = *(const float4*)(Wl + k4*8 + 4);
        a0 = fmaf(x.x, wA.x, a0); a1 = fmaf(x.x, wA.y, a1);
        a0 = fmaf(x.y, wA.z, a0); a1 = fmaf(x.y, wA.w, a1);
        a0 = fmaf(x.z, wB.x, a0); a1 = fmaf(x.z, wB.y, a1);
        a0 = fmaf(x.w, wB.z, a0); a1 = fmaf(x.w, wB.w, a1);
    }
    float2 r; r.x = a0; r.y = a1;
    *(float2*)(outp + (size_t)v*2) = r;
}

// ---------------- orchestration ----------------
static void run_type(const float* x, const int* ei, int E,
                     const float* W1, const float* b1,
                     const float* W2, const float* b2,
                     const float* Wl, const float* bl,
                     float* out, int N,
                     float* bufA, float* bufB, float* dinv,
                     int* rowptr, int* csr_src, unsigned int* bucketed,
                     int* bhist, int* boff, int* gcursor,
                     unsigned short* Bhi, unsigned short* Blo,
                     hipStream_t stream){
    const int* src = ei;
    const int* dst = ei + E;
    const int NB = CDIV(N, NPB);

    // CSR build (bucketed; reused by both layers)
    hipMemsetAsync(bhist, 0, (size_t)NB * sizeof(int), stream);
    hg_bhist<<<CDIV(E,4096), 256, NB*sizeof(int), stream>>>(dst, bhist, E, NB);
    hg_bscan<<<1, 1024, 0, stream>>>(bhist, boff, NB, E);
    hipMemcpyAsync(gcursor, boff, (size_t)NB * sizeof(int), hipMemcpyDeviceToDevice, stream);
    hg_partition<<<CDIV(E,4096), 256, 2*NB*sizeof(int), stream>>>(src, dst, gcursor, bucketed, E, NB);
    hg_bucket_build<<<NB, 256, 0, stream>>>(bucketed, boff, dinv, rowptr, csr_src, N, E);

    // layer 1 (K=128)
    hg_wsplit<<<CDIV(4*4*64,256), 256, 0, stream>>>(W1, Bhi, Blo, 128);
    hg_gemm_mfma<128><<<CDIV(N,64), 256, 0, stream>>>(x, Bhi, Blo, dinv, bufA, N);
    hg_aggregate4<<<CDIV(N,16), 256, 0, stream>>>(bufA, csr_src, rowptr, dinv, b1, bufB, N);

    // layer 2 (K=64)
    hg_wsplit<<<CDIV(2*4*64,256), 256, 0, stream>>>(W2, Bhi, Blo, 64);
    hg_gemm_mfma<64><<<CDIV(N,64), 256, 0, stream>>>(bufB, Bhi, Blo, dinv, bufA, N);
    hg_aggregate4<<<CDIV(N,16), 256, 0, stream>>>(bufA, csr_src, rowptr, dinv, b2, bufB, N);

    // head
    hg_head<<<CDIV(N,256), 256, 0, stream>>>(bufB, Wl, bl, out, N);
}

extern "C" void kernel_launch(void* const* d_in, const int* in_sizes, int n_in,
                              void* d_out, int out_size, void* d_ws, size_t ws_size,
                              hipStream_t stream) {
    const float* x_user = (const float*)d_in[0];
    const float* x_item = (const float*)d_in[1];
    const int*  ei_user = (const int*)d_in[2];
    const int*  ei_item = (const int*)d_in[3];
    const float* W1_user = (const float*)d_in[4];
    const float* b1_user = (const float*)d_in[5];
    const float* W1_item = (const float*)d_in[6];
    const float* b1_item = (const float*)d_in[7];
    const float* W2_user = (const float*)d_in[8];
    const float* b2_user = (const float*)d_in[9];
    const float* W2_item = (const float*)d_in[10];
    const float* b2_item = (const float*)d_in[11];
    const float* Wl_user = (const float*)d_in[12];
    const float* bl_user = (const float*)d_in[13];
    const float* Wl_item = (const float*)d_in[14];
    const float* bl_item = (const float*)d_in[15];

    const int N_user = in_sizes[0] / 128;
    const int N_item = in_sizes[1] / 128;
    const int E_user = in_sizes[2] / 2;
    const int E_item = in_sizes[3] / 2;
    const int NMAX = (N_user > N_item) ? N_user : N_item;
    const int EMAX = (E_user > E_item) ? E_user : E_item;
    const int NBMAX = CDIV(NMAX, NPB);

    char* w = (char*)d_ws;
    float* bufA    = (float*)w;        w += (size_t)NMAX * 64 * sizeof(float);
    float* bufB    = (float*)w;        w += (size_t)NMAX * 64 * sizeof(float);
    float* dinv    = (float*)w;        w += (size_t)NMAX * sizeof(float);
    int*   rowptr  = (int*)w;          w += ((size_t)NMAX + 1) * sizeof(int);
    int*   csr_src = (int*)w;          w += (size_t)EMAX * sizeof(int);
    unsigned int* bucketed = (unsigned int*)w;  w += (size_t)EMAX * sizeof(int);
    int*   bhist   = (int*)w;          w += (size_t)NBMAX * sizeof(int);
    int*   boff    = (int*)w;          w += ((size_t)NBMAX + 1) * sizeof(int);
    int*   gcursor = (int*)w;          w += (size_t)NBMAX * sizeof(int);
    unsigned short* Bhi = (unsigned short*)w;   w += (size_t)128 * 64 * sizeof(unsigned short);
    unsigned short* Blo = (unsigned short*)w;   w += (size_t)128 * 64 * sizeof(unsigned short);

    float* out = (float*)d_out;

    run_type(x_user, ei_user, E_user, W1_user, b1_user, W2_user, b2_user, Wl_user, bl_user,
             out, N_user, bufA, bufB, dinv, rowptr, csr_src, bucketed, bhist, boff, gcursor,
             Bhi, Blo, stream);
    run_type(x_item, ei_item, E_item, W1_item, b1_item, W2_item, b2_item, Wl_item, bl_item,
             out + (size_t)2 * N_user, N_item, bufA, bufB, dinv, rowptr, csr_src, bucketed, bhist, boff, gcursor,
             Bhi, Blo, stream);
}

// Round 8
// 355.787 us; speedup vs baseline: 3.0924x; 1.2890x over previous
//
#include <hip/hip_runtime.h>

#define CDIV(a,b) (((a)+(b)-1)/(b))
#define NPB 256   // nodes per bucket; bucket(d) = d >> 8

typedef __attribute__((ext_vector_type(8))) short bf16x8;
typedef __attribute__((ext_vector_type(8))) unsigned short u16x8;
typedef __attribute__((ext_vector_type(4))) float f32x4;

__device__ __forceinline__ unsigned short f2bf(float x){
    unsigned int u = __float_as_uint(x);
    unsigned int r = u + 0x7FFFu + ((u >> 16) & 1u);   // RNE
    return (unsigned short)(r >> 16);
}
__device__ __forceinline__ float bf2f(unsigned short h){
    return __uint_as_float(((unsigned int)h) << 16);
}

// ---------------- phase A0: global bucket histogram (LDS-staged) ----------------
__global__ __launch_bounds__(256) void hg_bhist(const int* __restrict__ dst, int* __restrict__ bhist,
                                                int E, int NB){
    extern __shared__ int sh[];                 // NB ints
    for (int i = threadIdx.x; i < NB; i += 256) sh[i] = 0;
    __syncthreads();
    const int e0 = blockIdx.x * 4096;
    const int eend = min(e0 + 4096, E);
    for (int e = e0 + threadIdx.x; e < eend; e += 256)
        atomicAdd(&sh[dst[e] >> 8], 1);
    __syncthreads();
    for (int i = threadIdx.x; i < NB; i += 256)
        if (sh[i]) atomicAdd(&bhist[i], sh[i]);
}

// ---------------- phase A-scan: exclusive scan of NB bucket counts ----------------
__global__ __launch_bounds__(1024) void hg_bscan(const int* __restrict__ bhist, int* __restrict__ boff,
                                                 int NB, int E){
    __shared__ int sh[1024];
    const int t = threadIdx.x;
    const int v = (t < NB) ? bhist[t] : 0;
    sh[t] = v;
    __syncthreads();
    for (int off = 1; off < 1024; off <<= 1){
        int x = 0;
        if (t >= off) x = sh[t-off];
        __syncthreads();
        if (t >= off) sh[t] += x;
        __syncthreads();
    }
    if (t < NB) boff[t] = sh[t] - v;
    if (t == 0) boff[NB] = E;
}

// ---------------- phase A1: partition edges into buckets, packed src|(dst&255)<<24 ----------------
__global__ __launch_bounds__(256) void hg_partition(const int* __restrict__ src, const int* __restrict__ dst,
                                                    int* __restrict__ gcursor, unsigned int* __restrict__ bucketed,
                                                    int E, int NB){
    extern __shared__ int sh[];                 // lcnt[NB] + lbase[NB]
    int* lcnt  = sh;
    int* lbase = sh + NB;
    for (int i = threadIdx.x; i < NB; i += 256) lcnt[i] = 0;
    __syncthreads();
    const int e0 = blockIdx.x * 4096;
    const int eend = min(e0 + 4096, E);
    int lpos[16];
    #pragma unroll
    for (int j = 0; j < 16; ++j){
        const int e = e0 + threadIdx.x + j*256;
        lpos[j] = (e < eend) ? atomicAdd(&lcnt[dst[e] >> 8], 1) : 0;
    }
    __syncthreads();
    for (int i = threadIdx.x; i < NB; i += 256){
        const int c = lcnt[i];
        lbase[i] = c ? atomicAdd(&gcursor[i], c) : 0;
    }
    __syncthreads();
    #pragma unroll
    for (int j = 0; j < 16; ++j){
        const int e = e0 + threadIdx.x + j*256;
        if (e < eend){
            const int d = dst[e];
            const unsigned int word = (unsigned int)src[e] | ((unsigned int)(d & 255) << 24);
            bucketed[lbase[d >> 8] + lpos[j]] = word;
        }
    }
}

// ---------------- phase B: per-bucket deg/dinv/rowptr/counting-sort ----------------
__global__ __launch_bounds__(256) void hg_bucket_build(const unsigned int* __restrict__ bucketed,
                                                       const int* __restrict__ boff,
                                                       float* __restrict__ dinv, int* __restrict__ rowptr,
                                                       int* __restrict__ csr_src, int N, int E){
    __shared__ int hist[NPB];
    __shared__ int sc[NPB];
    __shared__ int cur[NPB];
    const int b   = blockIdx.x;
    const int t   = threadIdx.x;
    const int beg = boff[b], end = boff[b+1];
    hist[t] = 0;
    __syncthreads();
    for (int i = beg + t; i < end; i += 256)
        atomicAdd(&hist[bucketed[i] >> 24], 1);
    __syncthreads();
    const int d = hist[t];
    sc[t] = d;
    __syncthreads();
    for (int off = 1; off < 256; off <<= 1){
        int x = 0;
        if (t >= off) x = sc[t-off];
        __syncthreads();
        if (t >= off) sc[t] += x;
        __syncthreads();
    }
    const int excl = sc[t] - d;
    const int v = b*NPB + t;
    if (v < N){
        dinv[v]   = rsqrtf((float)(d + 1));     // +1 self-loop
        rowptr[v] = beg + excl;
    }
    if (b == 0 && t == 0) rowptr[N] = E;
    cur[t] = beg + excl;
    __syncthreads();
    for (int i = beg + t; i < end; i += 256){
        const unsigned int w = bucketed[i];
        const int p = atomicAdd(&cur[w >> 24], 1);
        csr_src[p] = (int)(w & 0x00FFFFFFu);
    }
}

// ---------------- W split+fragment-order prep ----------------
__global__ __launch_bounds__(256) void hg_wsplit(const float* __restrict__ W,
                                                 unsigned short* __restrict__ Bhi,
                                                 unsigned short* __restrict__ Blo, int K){
    const int slot = blockIdx.x*256 + threadIdx.x;
    const int total = (K/32)*4*64;
    if (slot >= total) return;
    const int l  = slot & 63;
    const int ct = (slot >> 6) & 3;
    const int ks = slot >> 8;
    const int kb = ks*32 + (l >> 4)*8;
    const int c  = ct*16 + (l & 15);
    #pragma unroll
    for (int j = 0; j < 8; ++j){
        const float w = W[(size_t)(kb + j)*64 + c];
        const unsigned short h = f2bf(w);
        Bhi[(size_t)slot*8 + j] = h;
        Blo[(size_t)slot*8 + j] = f2bf(w - bf2f(h));
    }
}

// ---------------- MFMA GEMM: Gbf[v][j] = bf16((X[v,:] @ W[:,j]) * dinv[v]) ----------------
template<int K>
__global__ __launch_bounds__(256) void hg_gemm_mfma(const float* __restrict__ X,
                                                    const unsigned short* __restrict__ Bhi,
                                                    const unsigned short* __restrict__ Blo,
                                                    const float* __restrict__ dinv,
                                                    unsigned short* __restrict__ G, int N){
    const int l = threadIdx.x & 63;
    const int w = threadIdx.x >> 6;
    const int row0 = blockIdx.x*64 + w*16;
    if (row0 >= N) return;

    f32x4 acc[4];
    #pragma unroll
    for (int ct = 0; ct < 4; ++ct) acc[ct] = (f32x4){0.f,0.f,0.f,0.f};

    const int rA = row0 + (l & 15);
    const int kg = (l >> 4) * 8;
    const bool rowok = (rA < N);
    const float* xrow = X + (size_t)rA * K;

    #pragma unroll
    for (int ks = 0; ks < K/32; ++ks){
        float xv[8];
        if (rowok){
            const float4 a = *(const float4*)(xrow + ks*32 + kg);
            const float4 b = *(const float4*)(xrow + ks*32 + kg + 4);
            xv[0]=a.x; xv[1]=a.y; xv[2]=a.z; xv[3]=a.w;
            xv[4]=b.x; xv[5]=b.y; xv[6]=b.z; xv[7]=b.w;
        } else {
            #pragma unroll
            for (int j = 0; j < 8; ++j) xv[j] = 0.f;
        }
        bf16x8 ahi, alo;
        #pragma unroll
        for (int j = 0; j < 8; ++j){
            const unsigned short h = f2bf(xv[j]);
            ahi[j] = (short)h;
            alo[j] = (short)f2bf(xv[j] - bf2f(h));
        }
        #pragma unroll
        for (int ct = 0; ct < 4; ++ct){
            const bf16x8 bhi = *(const bf16x8*)(Bhi + ((size_t)(ks*4 + ct)*64 + l)*8);
            const bf16x8 blo = *(const bf16x8*)(Blo + ((size_t)(ks*4 + ct)*64 + l)*8);
            acc[ct] = __builtin_amdgcn_mfma_f32_16x16x32_bf16(ahi, bhi, acc[ct], 0, 0, 0);
            acc[ct] = __builtin_amdgcn_mfma_f32_16x16x32_bf16(alo, bhi, acc[ct], 0, 0, 0);
            acc[ct] = __builtin_amdgcn_mfma_f32_16x16x32_bf16(ahi, blo, acc[ct], 0, 0, 0);
        }
    }

    const int orow0 = row0 + (l >> 4)*4;
    const int ocol  = l & 15;
    #pragma unroll
    for (int r = 0; r < 4; ++r){
        const int orow = orow0 + r;
        if (orow < N){
            const float dv = dinv[orow];
            #pragma unroll
            for (int ct = 0; ct < 4; ++ct)
                G[(size_t)orow*64 + ct*16 + ocol] = f2bf(acc[ct][r] * dv);
        }
    }
}

// ---------------- gather-aggregate (bf16 G): 8 nodes/wave, 8 lanes x bf16x8 per node ----------------
// out = relu((sum_in g[s] + g[v]) * dinv[v] + b); fp32 accumulation
__global__ __launch_bounds__(256) void hg_aggregate8(const unsigned short* __restrict__ g,
                                                     const int* __restrict__ csr_src,
                                                     const int* __restrict__ rowptr,
                                                     const float* __restrict__ dinv,
                                                     const float* __restrict__ b,
                                                     float* __restrict__ outp, int N){
    const int wave = (blockIdx.x*256 + threadIdx.x) >> 6;
    const int sub  = (threadIdx.x >> 3) & 7;      // node slot within wave (0..7)
    const int c8   = (threadIdx.x & 7) << 3;      // feature offset (0,8,...,56)
    const int v    = wave*8 + sub;
    const bool ok  = (v < N);

    int beg = 0, cnt = 0;
    if (ok){ beg = rowptr[v]; cnt = rowptr[v+1] - beg; }

    float acc[8];
    #pragma unroll
    for (int j = 0; j < 8; ++j) acc[j] = 0.f;
    if (ok){
        const u16x8 s = *(const u16x8*)(g + (size_t)v*64 + c8);   // self-loop term
        #pragma unroll
        for (int j = 0; j < 8; ++j) acc[j] = bf2f(s[j]);
    }

    int i = 0;
    for (; i + 8 <= cnt; i += 8){
        const int s0 = csr_src[beg+i+0]; const int s1 = csr_src[beg+i+1];
        const int s2 = csr_src[beg+i+2]; const int s3 = csr_src[beg+i+3];
        const int s4 = csr_src[beg+i+4]; const int s5 = csr_src[beg+i+5];
        const int s6 = csr_src[beg+i+6]; const int s7 = csr_src[beg+i+7];
        const u16x8 x0 = *(const u16x8*)(g + (size_t)s0*64 + c8);
        const u16x8 x1 = *(const u16x8*)(g + (size_t)s1*64 + c8);
        const u16x8 x2 = *(const u16x8*)(g + (size_t)s2*64 + c8);
        const u16x8 x3 = *(const u16x8*)(g + (size_t)s3*64 + c8);
        const u16x8 x4 = *(const u16x8*)(g + (size_t)s4*64 + c8);
        const u16x8 x5 = *(const u16x8*)(g + (size_t)s5*64 + c8);
        const u16x8 x6 = *(const u16x8*)(g + (size_t)s6*64 + c8);
        const u16x8 x7 = *(const u16x8*)(g + (size_t)s7*64 + c8);
        #pragma unroll
        for (int j = 0; j < 8; ++j){
            acc[j] += (bf2f(x0[j]) + bf2f(x1[j])) + (bf2f(x2[j]) + bf2f(x3[j]))
                    + (bf2f(x4[j]) + bf2f(x5[j])) + (bf2f(x6[j]) + bf2f(x7[j]));
        }
    }
    for (; i + 4 <= cnt; i += 4){
        const int s0 = csr_src[beg+i+0]; const int s1 = csr_src[beg+i+1];
        const int s2 = csr_src[beg+i+2]; const int s3 = csr_src[beg+i+3];
        const u16x8 x0 = *(const u16x8*)(g + (size_t)s0*64 + c8);
        const u16x8 x1 = *(const u16x8*)(g + (size_t)s1*64 + c8);
        const u16x8 x2 = *(const u16x8*)(g + (size_t)s2*64 + c8);
        const u16x8 x3 = *(const u16x8*)(g + (size_t)s3*64 + c8);
        #pragma unroll
        for (int j = 0; j < 8; ++j)
            acc[j] += (bf2f(x0[j]) + bf2f(x1[j])) + (bf2f(x2[j]) + bf2f(x3[j]));
    }
    for (; i < cnt; ++i){
        const u16x8 x0 = *(const u16x8*)(g + (size_t)csr_src[beg+i]*64 + c8);
        #pragma unroll
        for (int j = 0; j < 8; ++j) acc[j] += bf2f(x0[j]);
    }

    if (ok){
        const float dv = dinv[v];
        float4 r0, r1;
        const float4 b0 = *(const float4*)(b + c8);
        const float4 b1 = *(const float4*)(b + c8 + 4);
        r0.x = fmaxf(fmaf(acc[0], dv, b0.x), 0.f);
        r0.y = fmaxf(fmaf(acc[1], dv, b0.y), 0.f);
        r0.z = fmaxf(fmaf(acc[2], dv, b0.z), 0.f);
        r0.w = fmaxf(fmaf(acc[3], dv, b0.w), 0.f);
        r1.x = fmaxf(fmaf(acc[4], dv, b1.x), 0.f);
        r1.y = fmaxf(fmaf(acc[5], dv, b1.y), 0.f);
        r1.z = fmaxf(fmaf(acc[6], dv, b1.z), 0.f);
        r1.w = fmaxf(fmaf(acc[7], dv, b1.w), 0.f);
        *(float4*)(outp + (size_t)v*64 + c8)     = r0;
        *(float4*)(outp + (size_t)v*64 + c8 + 4) = r1;
    }
}

// ---------------- head: out[v][0:2] = H[v,:] @ Wl + bl ----------------
__global__ __launch_bounds__(256) void hg_head(const float* __restrict__ H, const float* __restrict__ Wl,
                                               const float* __restrict__ bl, float* __restrict__ outp, int N){
    int v = blockIdx.x*256 + threadIdx.x;
    if (v >= N) return;
    const float* h = H + (size_t)v*64;
    float a0 = bl[0], a1 = bl[1];
    #pragma unroll
    for (int k4 = 0; k4 < 16; ++k4) {
        const float4 x = *(const float4*)(h + k4*4);
        const float4 wA = *(const float4*)(Wl + k4*8 + 0);
        const float4 wB = *(const float4*)(Wl + k4*8 + 4);
        a0 = fmaf(x.x, wA.x, a0); a1 = fmaf(x.x, wA.y, a1);
        a0 = fmaf(x.y, wA.z, a0); a1 = fmaf(x.y, wA.w, a1);
        a0 = fmaf(x.z, wB.x, a0); a1 = fmaf(x.z, wB.y, a1);
        a0 = fmaf(x.w, wB.z, a0); a1 = fmaf(x.w, wB.w, a1);
    }
    float2 r; r.x = a0; r.y = a1;
    *(float2*)(outp + (size_t)v*2) = r;
}

// ---------------- orchestration ----------------
static void run_type(const float* x, const int* ei, int E,
                     const float* W1, const float* b1,
                     const float* W2, const float* b2,
                     const float* Wl, const float* bl,
                     float* out, int N,
                     float* hF, unsigned short* Gbf, float* dinv,
                     int* rowptr, int* csr_src, unsigned int* bucketed,
                     int* bhist, int* boff, int* gcursor,
                     unsigned short* Bhi, unsigned short* Blo,
                     hipStream_t stream){
    const int* src = ei;
    const int* dst = ei + E;
    const int NB = CDIV(N, NPB);

    // CSR build (bucketed; reused by both layers)
    hipMemsetAsync(bhist, 0, (size_t)NB * sizeof(int), stream);
    hg_bhist<<<CDIV(E,4096), 256, NB*sizeof(int), stream>>>(dst, bhist, E, NB);
    hg_bscan<<<1, 1024, 0, stream>>>(bhist, boff, NB, E);
    hipMemcpyAsync(gcursor, boff, (size_t)NB * sizeof(int), hipMemcpyDeviceToDevice, stream);
    hg_partition<<<CDIV(E,4096), 256, 2*NB*sizeof(int), stream>>>(src, dst, gcursor, bucketed, E, NB);
    hg_bucket_build<<<NB, 256, 0, stream>>>(bucketed, boff, dinv, rowptr, csr_src, N, E);

    // layer 1 (K=128): x -> Gbf -> hF
    hg_wsplit<<<CDIV(4*4*64,256), 256, 0, stream>>>(W1, Bhi, Blo, 128);
    hg_gemm_mfma<128><<<CDIV(N,64), 256, 0, stream>>>(x, Bhi, Blo, dinv, Gbf, N);
    hg_aggregate8<<<CDIV(N,32), 256, 0, stream>>>(Gbf, csr_src, rowptr, dinv, b1, hF, N);

    // layer 2 (K=64): hF -> Gbf -> hF
    hg_wsplit<<<CDIV(2*4*64,256), 256, 0, stream>>>(W2, Bhi, Blo, 64);
    hg_gemm_mfma<64><<<CDIV(N,64), 256, 0, stream>>>(hF, Bhi, Blo, dinv, Gbf, N);
    hg_aggregate8<<<CDIV(N,32), 256, 0, stream>>>(Gbf, csr_src, rowptr, dinv, b2, hF, N);

    // head
    hg_head<<<CDIV(N,256), 256, 0, stream>>>(hF, Wl, bl, out, N);
}

extern "C" void kernel_launch(void* const* d_in, const int* in_sizes, int n_in,
                              void* d_out, int out_size, void* d_ws, size_t ws_size,
                              hipStream_t stream) {
    const float* x_user = (const float*)d_in[0];
    const float* x_item = (const float*)d_in[1];
    const int*  ei_user = (const int*)d_in[2];
    const int*  ei_item = (const int*)d_in[3];
    const float* W1_user = (const float*)d_in[4];
    const float* b1_user = (const float*)d_in[5];
    const float* W1_item = (const float*)d_in[6];
    const float* b1_item = (const float*)d_in[7];
    const float* W2_user = (const float*)d_in[8];
    const float* b2_user = (const float*)d_in[9];
    const float* W2_item = (const float*)d_in[10];
    const float* b2_item = (const float*)d_in[11];
    const float* Wl_user = (const float*)d_in[12];
    const float* bl_user = (const float*)d_in[13];
    const float* Wl_item = (const float*)d_in[14];
    const float* bl_item = (const float*)d_in[15];

    const int N_user = in_sizes[0] / 128;
    const int N_item = in_sizes[1] / 128;
    const int E_user = in_sizes[2] / 2;
    const int E_item = in_sizes[3] / 2;
    const int NMAX = (N_user > N_item) ? N_user : N_item;
    const int EMAX = (E_user > E_item) ? E_user : E_item;
    const int NBMAX = CDIV(NMAX, NPB);

    char* w = (char*)d_ws;
    float* hF      = (float*)w;        w += (size_t)NMAX * 64 * sizeof(float);
    unsigned short* Gbf = (unsigned short*)w;   w += (size_t)NMAX * 64 * sizeof(unsigned short);
    float* dinv    = (float*)w;        w += (size_t)NMAX * sizeof(float);
    int*   rowptr  = (int*)w;          w += ((size_t)NMAX + 1) * sizeof(int);
    int*   csr_src = (int*)w;          w += (size_t)EMAX * sizeof(int);
    unsigned int* bucketed = (unsigned int*)w;  w += (size_t)EMAX * sizeof(int);
    int*   bhist   = (int*)w;          w += (size_t)NBMAX * sizeof(int);
    int*   boff    = (int*)w;          w += ((size_t)NBMAX + 1) * sizeof(int);
    int*   gcursor = (int*)w;          w += (size_t)NBMAX * sizeof(int);
    unsigned short* Bhi = (unsigned short*)w;   w += (size_t)128 * 64 * sizeof(unsigned short);
    unsigned short* Blo = (unsigned short*)w;   w += (size_t)128 * 64 * sizeof(unsigned short);

    float* out = (float*)d_out;

    run_type(x_user, ei_user, E_user, W1_user, b1_user, W2_user, b2_user, Wl_user, bl_user,
             out, N_user, hF, Gbf, dinv, rowptr, csr_src, bucketed, bhist, boff, gcursor,
             Bhi, Blo, stream);
    run_type(x_item, ei_item, E_item, W1_item, b1_item, W2_item, b2_item, Wl_item, bl_item,
             out + (size_t)2 * N_user, N_item, hF, Gbf, dinv, rowptr, csr_src, bucketed, bhist, boff, gcursor,
             Bhi, Blo, stream);
}

// Round 9
// 300.348 us; speedup vs baseline: 3.6632x; 1.1846x over previous
//
#include <hip/hip_runtime.h>

#define CDIV(a,b) (((a)+(b)-1)/(b))
#define NPB 256   // nodes per bucket; bucket(d) = d >> 8

typedef __attribute__((ext_vector_type(8))) short bf16x8;
typedef __attribute__((ext_vector_type(8))) unsigned short u16x8;
typedef __attribute__((ext_vector_type(4))) float f32x4;

__device__ __forceinline__ unsigned short f2bf(float x){
    unsigned int u = __float_as_uint(x);
    unsigned int r = u + 0x7FFFu + ((u >> 16) & 1u);   // RNE
    return (unsigned short)(r >> 16);
}
__device__ __forceinline__ float bf2f(unsigned short h){
    return __uint_as_float(((unsigned int)h) << 16);
}

// ---------------- wsplit for all 4 weight matrices in one launch ----------------
// element layout per matrix: slot=((ks*4+ct)*64+l), elem j = W[ks*32+(l>>4)*8+j][ct*16+(l&15)]
__global__ __launch_bounds__(256) void hg_wsplit_all(const float* __restrict__ W1u, const float* __restrict__ W1i,
                                                     const float* __restrict__ W2u, const float* __restrict__ W2i,
                                                     unsigned short* __restrict__ Bhi, unsigned short* __restrict__ Blo){
    const int sid = blockIdx.x*256 + threadIdx.x;   // 0..3071
    if (sid >= 3072) return;
    const float* W; int slot, base;
    if (sid < 1024)      { W = W1u; slot = sid;        base = 0;     }
    else if (sid < 2048) { W = W1i; slot = sid - 1024; base = 8192;  }
    else if (sid < 2560) { W = W2u; slot = sid - 2048; base = 16384; }
    else                 { W = W2i; slot = sid - 2560; base = 20480; }
    const int l  = slot & 63;
    const int ct = (slot >> 6) & 3;
    const int ks = slot >> 8;
    const int kb = ks*32 + (l >> 4)*8;
    const int c  = ct*16 + (l & 15);
    #pragma unroll
    for (int j = 0; j < 8; ++j){
        const float w = W[(size_t)(kb + j)*64 + c];
        const unsigned short h = f2bf(w);
        Bhi[(size_t)base + (size_t)slot*8 + j] = h;
        Blo[(size_t)base + (size_t)slot*8 + j] = f2bf(w - bf2f(h));
    }
}

// ---------------- dual bucket histogram ----------------
__global__ __launch_bounds__(256) void hg_bhist2(const int* __restrict__ dstU, const int* __restrict__ dstI,
                                                 int* __restrict__ bhU, int* __restrict__ bhI,
                                                 int EU, int EI, int nbU, int NB){
    extern __shared__ int sh[];
    const int type = (blockIdx.x >= nbU);
    const int blk  = type ? blockIdx.x - nbU : blockIdx.x;
    const int* dst = type ? dstI : dstU;
    int* bh        = type ? bhI  : bhU;
    const int E    = type ? EI   : EU;
    for (int i = threadIdx.x; i < NB; i += 256) sh[i] = 0;
    __syncthreads();
    const int e0 = blk * 4096;
    const int eend = min(e0 + 4096, E);
    for (int e = e0 + threadIdx.x; e < eend; e += 256)
        atomicAdd(&sh[dst[e] >> 8], 1);
    __syncthreads();
    for (int i = threadIdx.x; i < NB; i += 256)
        if (sh[i]) atomicAdd(&bh[i], sh[i]);
}

// ---------------- dual exclusive scan (block 0 = user, block 1 = item); also fills gcursor ----
__global__ __launch_bounds__(1024) void hg_bscan2(const int* __restrict__ bhU, const int* __restrict__ bhI,
                                                  int* __restrict__ boffU, int* __restrict__ boffI,
                                                  int* __restrict__ gcurU, int* __restrict__ gcurI,
                                                  int NB, int EU, int EI){
    __shared__ int sh[1024];
    const int type = blockIdx.x;
    const int* bh = type ? bhI : bhU;
    int* boff     = type ? boffI : boffU;
    int* gcur     = type ? gcurI : gcurU;
    const int E   = type ? EI : EU;
    const int t = threadIdx.x;
    const int v = (t < NB) ? bh[t] : 0;
    sh[t] = v;
    __syncthreads();
    for (int off = 1; off < 1024; off <<= 1){
        int x = 0;
        if (t >= off) x = sh[t-off];
        __syncthreads();
        if (t >= off) sh[t] += x;
        __syncthreads();
    }
    if (t < NB){ const int e = sh[t] - v; boff[t] = e; gcur[t] = e; }
    if (t == 0) boff[NB] = E;
}

// ---------------- dual partition ----------------
__global__ __launch_bounds__(256) void hg_partition2(const int* __restrict__ eiU, const int* __restrict__ eiI,
                                                     int* __restrict__ gcurU, int* __restrict__ gcurI,
                                                     unsigned int* __restrict__ bkU, unsigned int* __restrict__ bkI,
                                                     int EU, int EI, int nbU, int NB){
    extern __shared__ int sh[];
    int* lcnt  = sh;
    int* lbase = sh + NB;
    const int type = (blockIdx.x >= nbU);
    const int blk  = type ? blockIdx.x - nbU : blockIdx.x;
    const int E    = type ? EI : EU;
    const int* src = type ? eiI : eiU;
    const int* dst = src + E;
    int* gcur      = type ? gcurI : gcurU;
    unsigned int* bucketed = type ? bkI : bkU;

    for (int i = threadIdx.x; i < NB; i += 256) lcnt[i] = 0;
    __syncthreads();
    const int e0 = blk * 4096;
    const int eend = min(e0 + 4096, E);
    int lpos[16];
    #pragma unroll
    for (int j = 0; j < 16; ++j){
        const int e = e0 + threadIdx.x + j*256;
        lpos[j] = (e < eend) ? atomicAdd(&lcnt[dst[e] >> 8], 1) : 0;
    }
    __syncthreads();
    for (int i = threadIdx.x; i < NB; i += 256){
        const int c = lcnt[i];
        lbase[i] = c ? atomicAdd(&gcur[i], c) : 0;
    }
    __syncthreads();
    #pragma unroll
    for (int j = 0; j < 16; ++j){
        const int e = e0 + threadIdx.x + j*256;
        if (e < eend){
            const int d = dst[e];
            const unsigned int word = (unsigned int)src[e] | ((unsigned int)(d & 255) << 24);
            bucketed[lbase[d >> 8] + lpos[j]] = word;
        }
    }
}

// ---------------- dual per-bucket deg/dinv/rowptr/counting-sort ----------------
__global__ __launch_bounds__(256) void hg_bucket_build2(const unsigned int* __restrict__ bkU, const unsigned int* __restrict__ bkI,
                                                        const int* __restrict__ boffU, const int* __restrict__ boffI,
                                                        float* __restrict__ dinvU, float* __restrict__ dinvI,
                                                        int* __restrict__ rowptrU, int* __restrict__ rowptrI,
                                                        int* __restrict__ csrU, int* __restrict__ csrI,
                                                        int NU, int NI, int EU, int EI, int nbU){
    __shared__ int hist[NPB];
    __shared__ int sc[NPB];
    __shared__ int cur[NPB];
    const int type = (blockIdx.x >= nbU);
    const int b    = type ? blockIdx.x - nbU : blockIdx.x;
    const unsigned int* bucketed = type ? bkI : bkU;
    const int* boff = type ? boffI : boffU;
    float* dinv     = type ? dinvI : dinvU;
    int* rowptr     = type ? rowptrI : rowptrU;
    int* csr_src    = type ? csrI : csrU;
    const int N     = type ? NI : NU;
    const int E     = type ? EI : EU;

    const int t   = threadIdx.x;
    const int beg = boff[b], end = boff[b+1];
    hist[t] = 0;
    __syncthreads();
    for (int i = beg + t; i < end; i += 256)
        atomicAdd(&hist[bucketed[i] >> 24], 1);
    __syncthreads();
    const int d = hist[t];
    sc[t] = d;
    __syncthreads();
    for (int off = 1; off < 256; off <<= 1){
        int x = 0;
        if (t >= off) x = sc[t-off];
        __syncthreads();
        if (t >= off) sc[t] += x;
        __syncthreads();
    }
    const int excl = sc[t] - d;
    const int v = b*NPB + t;
    if (v < N){
        dinv[v]   = rsqrtf((float)(d + 1));     // +1 self-loop
        rowptr[v] = beg + excl;
    }
    if (b == 0 && t == 0) rowptr[N] = E;
    cur[t] = beg + excl;
    __syncthreads();
    for (int i = beg + t; i < end; i += 256){
        const unsigned int w = bucketed[i];
        const int p = atomicAdd(&cur[w >> 24], 1);
        csr_src[p] = (int)(w & 0x00FFFFFFu);
    }
}

// ---------------- dual MFMA GEMM: Gbf[v][j] = bf16((X[v,:] @ W[:,j]) * dinv[v]) ----------------
template<int K>
__global__ __launch_bounds__(256) void hg_gemm_mfma2(const float* __restrict__ XU, const float* __restrict__ XI,
                                                     const unsigned short* __restrict__ Bhi, const unsigned short* __restrict__ Blo,
                                                     int baseU, int baseI,
                                                     const float* __restrict__ dinvU, const float* __restrict__ dinvI,
                                                     unsigned short* __restrict__ GU, unsigned short* __restrict__ GI,
                                                     int NU, int NI, int nbU){
    const int type = (blockIdx.x >= nbU);
    const int blk  = type ? blockIdx.x - nbU : blockIdx.x;
    const float* X = type ? XI : XU;
    const float* dinv = type ? dinvI : dinvU;
    unsigned short* G = type ? GI : GU;
    const int N    = type ? NI : NU;
    const unsigned short* Bh = Bhi + (type ? baseI : baseU);
    const unsigned short* Bl = Blo + (type ? baseI : baseU);

    const int l = threadIdx.x & 63;
    const int w = threadIdx.x >> 6;
    const int row0 = blk*64 + w*16;
    if (row0 >= N) return;

    f32x4 acc[4];
    #pragma unroll
    for (int ct = 0; ct < 4; ++ct) acc[ct] = (f32x4){0.f,0.f,0.f,0.f};

    const int rA = row0 + (l & 15);
    const int kg = (l >> 4) * 8;
    const bool rowok = (rA < N);
    const float* xrow = X + (size_t)rA * K;

    #pragma unroll
    for (int ks = 0; ks < K/32; ++ks){
        float xv[8];
        if (rowok){
            const float4 a = *(const float4*)(xrow + ks*32 + kg);
            const float4 b = *(const float4*)(xrow + ks*32 + kg + 4);
            xv[0]=a.x; xv[1]=a.y; xv[2]=a.z; xv[3]=a.w;
            xv[4]=b.x; xv[5]=b.y; xv[6]=b.z; xv[7]=b.w;
        } else {
            #pragma unroll
            for (int j = 0; j < 8; ++j) xv[j] = 0.f;
        }
        bf16x8 ahi, alo;
        #pragma unroll
        for (int j = 0; j < 8; ++j){
            const unsigned short h = f2bf(xv[j]);
            ahi[j] = (short)h;
            alo[j] = (short)f2bf(xv[j] - bf2f(h));
        }
        #pragma unroll
        for (int ct = 0; ct < 4; ++ct){
            const bf16x8 bhi = *(const bf16x8*)(Bh + ((size_t)(ks*4 + ct)*64 + l)*8);
            const bf16x8 blo = *(const bf16x8*)(Bl + ((size_t)(ks*4 + ct)*64 + l)*8);
            acc[ct] = __builtin_amdgcn_mfma_f32_16x16x32_bf16(ahi, bhi, acc[ct], 0, 0, 0);
            acc[ct] = __builtin_amdgcn_mfma_f32_16x16x32_bf16(alo, bhi, acc[ct], 0, 0, 0);
            acc[ct] = __builtin_amdgcn_mfma_f32_16x16x32_bf16(ahi, blo, acc[ct], 0, 0, 0);
        }
    }

    const int orow0 = row0 + (l >> 4)*4;
    const int ocol  = l & 15;
    #pragma unroll
    for (int r = 0; r < 4; ++r){
        const int orow = orow0 + r;
        if (orow < N){
            const float dv = dinv[orow];
            #pragma unroll
            for (int ct = 0; ct < 4; ++ct)
                G[(size_t)orow*64 + ct*16 + ocol] = f2bf(acc[ct][r] * dv);
        }
    }
}

// ---------------- dual gather-aggregate (bf16 G): 8 nodes/wave, 8 lanes x bf16x8 per node ----
__global__ __launch_bounds__(256) void hg_aggregate2(const unsigned short* __restrict__ gU, const unsigned short* __restrict__ gI,
                                                     const int* __restrict__ csrU, const int* __restrict__ csrI,
                                                     const int* __restrict__ rowptrU, const int* __restrict__ rowptrI,
                                                     const float* __restrict__ dinvU, const float* __restrict__ dinvI,
                                                     const float* __restrict__ bU, const float* __restrict__ bI,
                                                     float* __restrict__ outU, float* __restrict__ outI,
                                                     int NU, int NI, int nbU){
    const int type = (blockIdx.x >= nbU);
    const int blk  = type ? blockIdx.x - nbU : blockIdx.x;
    const unsigned short* g = type ? gI : gU;
    const int* csr_src = type ? csrI : csrU;
    const int* rowptr  = type ? rowptrI : rowptrU;
    const float* dinv  = type ? dinvI : dinvU;
    const float* b     = type ? bI : bU;
    float* outp        = type ? outI : outU;
    const int N        = type ? NI : NU;

    const int wave = (blk*256 + (int)threadIdx.x) >> 6;
    const int sub  = (threadIdx.x >> 3) & 7;
    const int c8   = (threadIdx.x & 7) << 3;
    const int v    = wave*8 + sub;
    const bool ok  = (v < N);

    int beg = 0, cnt = 0;
    if (ok){ beg = rowptr[v]; cnt = rowptr[v+1] - beg; }

    float acc[8];
    #pragma unroll
    for (int j = 0; j < 8; ++j) acc[j] = 0.f;
    if (ok){
        const u16x8 s = *(const u16x8*)(g + (size_t)v*64 + c8);
        #pragma unroll
        for (int j = 0; j < 8; ++j) acc[j] = bf2f(s[j]);
    }

    int i = 0;
    for (; i + 8 <= cnt; i += 8){
        const int s0 = csr_src[beg+i+0]; const int s1 = csr_src[beg+i+1];
        const int s2 = csr_src[beg+i+2]; const int s3 = csr_src[beg+i+3];
        const int s4 = csr_src[beg+i+4]; const int s5 = csr_src[beg+i+5];
        const int s6 = csr_src[beg+i+6]; const int s7 = csr_src[beg+i+7];
        const u16x8 x0 = *(const u16x8*)(g + (size_t)s0*64 + c8);
        const u16x8 x1 = *(const u16x8*)(g + (size_t)s1*64 + c8);
        const u16x8 x2 = *(const u16x8*)(g + (size_t)s2*64 + c8);
        const u16x8 x3 = *(const u16x8*)(g + (size_t)s3*64 + c8);
        const u16x8 x4 = *(const u16x8*)(g + (size_t)s4*64 + c8);
        const u16x8 x5 = *(const u16x8*)(g + (size_t)s5*64 + c8);
        const u16x8 x6 = *(const u16x8*)(g + (size_t)s6*64 + c8);
        const u16x8 x7 = *(const u16x8*)(g + (size_t)s7*64 + c8);
        #pragma unroll
        for (int j = 0; j < 8; ++j){
            acc[j] += (bf2f(x0[j]) + bf2f(x1[j])) + (bf2f(x2[j]) + bf2f(x3[j]))
                    + (bf2f(x4[j]) + bf2f(x5[j])) + (bf2f(x6[j]) + bf2f(x7[j]));
        }
    }
    for (; i + 4 <= cnt; i += 4){
        const int s0 = csr_src[beg+i+0]; const int s1 = csr_src[beg+i+1];
        const int s2 = csr_src[beg+i+2]; const int s3 = csr_src[beg+i+3];
        const u16x8 x0 = *(const u16x8*)(g + (size_t)s0*64 + c8);
        const u16x8 x1 = *(const u16x8*)(g + (size_t)s1*64 + c8);
        const u16x8 x2 = *(const u16x8*)(g + (size_t)s2*64 + c8);
        const u16x8 x3 = *(const u16x8*)(g + (size_t)s3*64 + c8);
        #pragma unroll
        for (int j = 0; j < 8; ++j)
            acc[j] += (bf2f(x0[j]) + bf2f(x1[j])) + (bf2f(x2[j]) + bf2f(x3[j]));
    }
    for (; i < cnt; ++i){
        const u16x8 x0 = *(const u16x8*)(g + (size_t)csr_src[beg+i]*64 + c8);
        #pragma unroll
        for (int j = 0; j < 8; ++j) acc[j] += bf2f(x0[j]);
    }

    if (ok){
        const float dv = dinv[v];
        float4 r0, r1;
        const float4 b0 = *(const float4*)(b + c8);
        const float4 b1 = *(const float4*)(b + c8 + 4);
        r0.x = fmaxf(fmaf(acc[0], dv, b0.x), 0.f);
        r0.y = fmaxf(fmaf(acc[1], dv, b0.y), 0.f);
        r0.z = fmaxf(fmaf(acc[2], dv, b0.z), 0.f);
        r0.w = fmaxf(fmaf(acc[3], dv, b0.w), 0.f);
        r1.x = fmaxf(fmaf(acc[4], dv, b1.x), 0.f);
        r1.y = fmaxf(fmaf(acc[5], dv, b1.y), 0.f);
        r1.z = fmaxf(fmaf(acc[6], dv, b1.z), 0.f);
        r1.w = fmaxf(fmaf(acc[7], dv, b1.w), 0.f);
        *(float4*)(outp + (size_t)v*64 + c8)     = r0;
        *(float4*)(outp + (size_t)v*64 + c8 + 4) = r1;
    }
}

// ---------------- dual head ----------------
__global__ __launch_bounds__(256) void hg_head2(const float* __restrict__ HU, const float* __restrict__ HI,
                                                const float* __restrict__ WlU, const float* __restrict__ WlI,
                                                const float* __restrict__ blU, const float* __restrict__ blI,
                                                float* __restrict__ outU, float* __restrict__ outI,
                                                int NU, int NI, int nbU){
    const int type = (blockIdx.x >= nbU);
    const int blk  = type ? blockIdx.x - nbU : blockIdx.x;
    const float* H  = type ? HI : HU;
    const float* Wl = type ? WlI : WlU;
    const float* bl = type ? blI : blU;
    float* outp     = type ? outI : outU;
    const int N     = type ? NI : NU;

    int v = blk*256 + threadIdx.x;
    if (v >= N) return;
    const float* h = H + (size_t)v*64;
    float a0 = bl[0], a1 = bl[1];
    #pragma unroll
    for (int k4 = 0; k4 < 16; ++k4) {
        const float4 x = *(const float4*)(h + k4*4);
        const float4 wA = *(const float4*)(Wl + k4*8 + 0);
        const float4 wB = *(const float4*)(Wl + k4*8 + 4);
        a0 = fmaf(x.x, wA.x, a0); a1 = fmaf(x.x, wA.y, a1);
        a0 = fmaf(x.y, wA.z, a0); a1 = fmaf(x.y, wA.w, a1);
        a0 = fmaf(x.z, wB.x, a0); a1 = fmaf(x.z, wB.y, a1);
        a0 = fmaf(x.w, wB.z, a0); a1 = fmaf(x.w, wB.w, a1);
    }
    float2 r; r.x = a0; r.y = a1;
    *(float2*)(outp + (size_t)v*2) = r;
}

extern "C" void kernel_launch(void* const* d_in, const int* in_sizes, int n_in,
                              void* d_out, int out_size, void* d_ws, size_t ws_size,
                              hipStream_t stream) {
    const float* x_user = (const float*)d_in[0];
    const float* x_item = (const float*)d_in[1];
    const int*  ei_user = (const int*)d_in[2];
    const int*  ei_item = (const int*)d_in[3];
    const float* W1_user = (const float*)d_in[4];
    const float* b1_user = (const float*)d_in[5];
    const float* W1_item = (const float*)d_in[6];
    const float* b1_item = (const float*)d_in[7];
    const float* W2_user = (const float*)d_in[8];
    const float* b2_user = (const float*)d_in[9];
    const float* W2_item = (const float*)d_in[10];
    const float* b2_item = (const float*)d_in[11];
    const float* Wl_user = (const float*)d_in[12];
    const float* bl_user = (const float*)d_in[13];
    const float* Wl_item = (const float*)d_in[14];
    const float* bl_item = (const float*)d_in[15];

    const int NU = in_sizes[0] / 128;
    const int NI = in_sizes[1] / 128;
    const int EU = in_sizes[2] / 2;
    const int EI = in_sizes[3] / 2;
    const int NBU = CDIV(NU, NPB);
    const int NBI = CDIV(NI, NPB);

    char* w = (char*)d_ws;
    // per-type feature buffers
    float* hFU = (float*)w;                     w += (size_t)NU * 64 * sizeof(float);
    float* hFI = (float*)w;                     w += (size_t)NI * 64 * sizeof(float);
    unsigned short* GU = (unsigned short*)w;    w += (size_t)NU * 64 * sizeof(unsigned short);
    unsigned short* GI = (unsigned short*)w;    w += (size_t)NI * 64 * sizeof(unsigned short);
    float* dinvU = (float*)w;                   w += (size_t)NU * sizeof(float);
    float* dinvI = (float*)w;                   w += (size_t)NI * sizeof(float);
    int* rowptrU = (int*)w;                     w += ((size_t)NU + 1) * sizeof(int);
    int* rowptrI = (int*)w;                     w += ((size_t)NI + 1) * sizeof(int);
    int* csrU = (int*)w;                        w += (size_t)EU * sizeof(int);
    int* csrI = (int*)w;                        w += (size_t)EI * sizeof(int);
    unsigned int* bkU = (unsigned int*)w;       w += (size_t)EU * sizeof(int);
    unsigned int* bkI = (unsigned int*)w;       w += (size_t)EI * sizeof(int);
    int* bhU = (int*)w;                         w += (size_t)NBU * sizeof(int);
    int* bhI = (int*)w;                         w += (size_t)NBI * sizeof(int);   // contiguous with bhU
    int* boffU = (int*)w;                       w += ((size_t)NBU + 1) * sizeof(int);
    int* boffI = (int*)w;                       w += ((size_t)NBI + 1) * sizeof(int);
    int* gcurU = (int*)w;                       w += (size_t)NBU * sizeof(int);
    int* gcurI = (int*)w;                       w += (size_t)NBI * sizeof(int);
    unsigned short* Bhi = (unsigned short*)w;   w += (size_t)24576 * sizeof(unsigned short);
    unsigned short* Blo = (unsigned short*)w;   w += (size_t)24576 * sizeof(unsigned short);

    float* out  = (float*)d_out;
    float* outU = out;
    float* outI = out + (size_t)2 * NU;

    const int NB = (NBU > NBI) ? NBU : NBI;     // same shapes in practice; kernels use NB for LDS extent

    // weight prep (independent of everything else)
    hg_wsplit_all<<<12, 256, 0, stream>>>(W1_user, W1_item, W2_user, W2_item, Bhi, Blo);

    // CSR build, both types in each launch
    hipMemsetAsync(bhU, 0, ((size_t)NBU + NBI) * sizeof(int), stream);
    const int pbU = CDIV(EU, 4096), pbI = CDIV(EI, 4096);
    hg_bhist2<<<pbU + pbI, 256, NB*sizeof(int), stream>>>(ei_user + EU, ei_item + EI, bhU, bhI, EU, EI, pbU, NB);
    hg_bscan2<<<2, 1024, 0, stream>>>(bhU, bhI, boffU, boffI, gcurU, gcurI, NB, EU, EI);
    hg_partition2<<<pbU + pbI, 256, 2*NB*sizeof(int), stream>>>(ei_user, ei_item, gcurU, gcurI, bkU, bkI, EU, EI, pbU, NB);
    hg_bucket_build2<<<NBU + NBI, 256, 0, stream>>>(bkU, bkI, boffU, boffI, dinvU, dinvI,
                                                    rowptrU, rowptrI, csrU, csrI, NU, NI, EU, EI, NBU);

    // layer 1 (K=128): x -> G -> hF
    const int gbU = CDIV(NU, 64), gbI = CDIV(NI, 64);
    hg_gemm_mfma2<128><<<gbU + gbI, 256, 0, stream>>>(x_user, x_item, Bhi, Blo, 0, 8192,
                                                      dinvU, dinvI, GU, GI, NU, NI, gbU);
    const int abU = CDIV(NU, 32), abI = CDIV(NI, 32);
    hg_aggregate2<<<abU + abI, 256, 0, stream>>>(GU, GI, csrU, csrI, rowptrU, rowptrI,
                                                 dinvU, dinvI, b1_user, b1_item, hFU, hFI, NU, NI, abU);

    // layer 2 (K=64): hF -> G -> hF
    hg_gemm_mfma2<64><<<gbU + gbI, 256, 0, stream>>>(hFU, hFI, Bhi, Blo, 16384, 20480,
                                                     dinvU, dinvI, GU, GI, NU, NI, gbU);
    hg_aggregate2<<<abU + abI, 256, 0, stream>>>(GU, GI, csrU, csrI, rowptrU, rowptrI,
                                                 dinvU, dinvI, b2_user, b2_item, hFU, hFI, NU, NI, abU);

    // head
    const int hbU = CDIV(NU, 256), hbI = CDIV(NI, 256);
    hg_head2<<<hbU + hbI, 256, 0, stream>>>(hFU, hFI, Wl_user, Wl_item, bl_user, bl_item,
                                            outU, outI, NU, NI, hbU);
}